// Round 1
// baseline (897.302 us; speedup 1.0000x reference)
//
#include <hip/hip_runtime.h>
#include <hip/hip_bf16.h>

// ---------------- problem constants (static pyramid) ----------------
#define NB 4
#define LQ 5440
#define DM 256
#define NH 8
#define NL 4
#define NP 4
#define OFFD 32
#define DH 32
#define MTOT (NB * LQ)        // 21760
#define OEN (NH * NL * NP * OFFD)  // 4096
#define NGRP (NH * NL * NP)   // 128

// ---------------- stage A: value projection, transposed output ----------------
// Vt[b][h][pos][d] = input_flatten[b][pos][:] . value_W[h*32+d][:] + value_b
__global__ __launch_bounds__(256) void k_value_proj(
    const float* __restrict__ X,    // (21760,256)
    const float* __restrict__ W,    // (256,256) row-major (n,k)
    const float* __restrict__ bias, // (256)
    float* __restrict__ Vt)         // (4,8,5440,32)
{
    __shared__ float As[16][64];
    __shared__ float Bs[16][64];
    int tid = threadIdx.x;
    int m0 = blockIdx.x * 64, n0 = blockIdx.y * 64;
    int tx = tid & 15, ty = tid >> 4;
    float acc[4][4] = {};
    int lrow = tid >> 2;        // 0..63
    int lk4  = (tid & 3) * 4;   // 0,4,8,12
    const float* Ap = X + (size_t)(m0 + lrow) * 256 + lk4;
    const float* Bp = W + (size_t)(n0 + lrow) * 256 + lk4;
    for (int kc = 0; kc < 256; kc += 16) {
        float4 av = *(const float4*)(Ap + kc);
        float4 bv = *(const float4*)(Bp + kc);
        __syncthreads();
        As[lk4 + 0][lrow] = av.x; As[lk4 + 1][lrow] = av.y;
        As[lk4 + 2][lrow] = av.z; As[lk4 + 3][lrow] = av.w;
        Bs[lk4 + 0][lrow] = bv.x; Bs[lk4 + 1][lrow] = bv.y;
        Bs[lk4 + 2][lrow] = bv.z; Bs[lk4 + 3][lrow] = bv.w;
        __syncthreads();
#pragma unroll
        for (int kk = 0; kk < 16; kk++) {
            float a[4], b[4];
            *(float4*)a = *(const float4*)&As[kk][ty * 4];
            *(float4*)b = *(const float4*)&Bs[kk][tx * 4];
#pragma unroll
            for (int i = 0; i < 4; i++)
#pragma unroll
                for (int j = 0; j < 4; j++) acc[i][j] += a[i] * b[j];
        }
    }
#pragma unroll
    for (int i = 0; i < 4; i++) {
        int m = m0 + ty * 4 + i;
        int b = m / LQ, q = m % LQ;
#pragma unroll
        for (int j = 0; j < 4; j++) {
            int n = n0 + tx * 4 + j;
            int h = n >> 5, d = n & 31;
            Vt[(((size_t)b * NH + h) * LQ + q) * DH + d] = acc[i][j] + bias[n];
        }
    }
}

// ---------------- stage B: fused oe GEMM + silu + group reduction ----------------
// oe[m][n] = silu(query[m][:] . We[n][:]),  n = gg*32 + d, gg=(h,l,k)
// offs[m][gg][c] = sum_d oe * SW[gg][d][c] + SB[gg][c]
// awl [m][gg]    = sum_d oe * AW[gg][d]    + AB[gg]
__global__ __launch_bounds__(256) void k_oe_fused(
    const float* __restrict__ Q,     // (21760,256)
    const float* __restrict__ We,    // (4096,256)
    const float* __restrict__ SW,    // (128,32,2)
    const float* __restrict__ SB,    // (128,2)
    const float* __restrict__ AW,    // (128,32)
    const float* __restrict__ AB,    // (128)
    float* __restrict__ offs_out,    // (M,128,2)
    float* __restrict__ aw_out)      // (M,128)
{
    __shared__ float As[8][128];
    __shared__ float Bs[8][128];
    int tid = threadIdx.x;
    int m0 = blockIdx.x * 128, n0 = blockIdx.y * 128;
    int tx = tid & 15, ty = tid >> 4;
    float acc[8][8];
#pragma unroll
    for (int i = 0; i < 8; i++)
#pragma unroll
        for (int j = 0; j < 8; j++) acc[i][j] = 0.f;

    int lrow = tid >> 1;        // 0..127
    int lk4  = (tid & 1) * 4;   // 0 or 4
    const float* Ap = Q  + (size_t)(m0 + lrow) * 256 + lk4;
    const float* Bp = We + (size_t)(n0 + lrow) * 256 + lk4;

    for (int kc = 0; kc < 256; kc += 8) {
        float4 av = *(const float4*)(Ap + kc);
        float4 bv = *(const float4*)(Bp + kc);
        __syncthreads();
        As[lk4 + 0][lrow] = av.x; As[lk4 + 1][lrow] = av.y;
        As[lk4 + 2][lrow] = av.z; As[lk4 + 3][lrow] = av.w;
        Bs[lk4 + 0][lrow] = bv.x; Bs[lk4 + 1][lrow] = bv.y;
        Bs[lk4 + 2][lrow] = bv.z; Bs[lk4 + 3][lrow] = bv.w;
        __syncthreads();
#pragma unroll
        for (int kk = 0; kk < 8; kk++) {
            float a[8], b[8];
            *(float4*)&a[0] = *(const float4*)&As[kk][ty * 8];
            *(float4*)&a[4] = *(const float4*)&As[kk][ty * 8 + 4];
            *(float4*)&b[0] = *(const float4*)&Bs[kk][tx * 8];
            *(float4*)&b[4] = *(const float4*)&Bs[kk][tx * 8 + 4];
#pragma unroll
            for (int i = 0; i < 8; i++)
#pragma unroll
                for (int j = 0; j < 8; j++) acc[i][j] += a[i] * b[j];
        }
    }

    // epilogue: this thread owns cols n0+tx*8 .. +8, all inside group gg
    int gg = blockIdx.y * 4 + (tx >> 2);      // global (h,l,k) group 0..127
    int dbase = (tx & 3) * 8;                 // d offset within group
    float w0[8], w1[8], wA[8];
#pragma unroll
    for (int j = 0; j < 8; j++) {
        int dd = gg * 32 + dbase + j;
        w0[j] = SW[dd * 2 + 0];
        w1[j] = SW[dd * 2 + 1];
        wA[j] = AW[dd];
    }
    float sb0 = SB[gg * 2 + 0], sb1 = SB[gg * 2 + 1], ab = AB[gg];
    bool writer = ((tx & 3) == 0);
#pragma unroll
    for (int i = 0; i < 8; i++) {
        float s0 = 0.f, s1 = 0.f, s2 = 0.f;
#pragma unroll
        for (int j = 0; j < 8; j++) {
            float x = acc[i][j];
            float su = x * (1.0f / (1.0f + __expf(-x)));  // silu
            s0 += su * w0[j];
            s1 += su * w1[j];
            s2 += su * wA[j];
        }
        // reduce over the 4 lanes (tx&3 = 0..3) owning this 32-col group
        s0 += __shfl_xor(s0, 1); s0 += __shfl_xor(s0, 2);
        s1 += __shfl_xor(s1, 1); s1 += __shfl_xor(s1, 2);
        s2 += __shfl_xor(s2, 1); s2 += __shfl_xor(s2, 2);
        if (writer) {
            int m = m0 + ty * 8 + i;
            size_t oidx = ((size_t)m * NGRP + gg) * 2;
            offs_out[oidx + 0] = s0 + sb0;
            offs_out[oidx + 1] = s1 + sb1;
            aw_out[(size_t)m * NGRP + gg] = s2 + ab;
        }
    }
}

// ---------------- stage C: softmax + bilinear sampling ----------------
__global__ __launch_bounds__(256) void k_sample(
    const float* __restrict__ Vt,    // (4,8,5440,32)
    const float* __restrict__ refp,  // (4,5440,4,2)
    const float* __restrict__ offs,  // (M,128,2)
    const float* __restrict__ awl,   // (M,128)
    float* __restrict__ attn_out)    // (M,256)
{
    int m = blockIdx.x;
    int tid = threadIdx.x;
    __shared__ float s_off[256];
    __shared__ float s_aw[128];
    __shared__ float s_ref[8];
    s_off[tid] = offs[(size_t)m * 256 + tid];
    if (tid < 128) s_aw[tid] = awl[(size_t)m * 128 + tid];
    if (tid < 8)   s_ref[tid] = refp[(size_t)m * 8 + tid];
    __syncthreads();

    int h = tid >> 5, d = tid & 31;
    // softmax over the 16 (l,k) logits of this head (redundant per lane, cheap)
    float mx = -1e30f;
#pragma unroll
    for (int i = 0; i < 16; i++) mx = fmaxf(mx, s_aw[h * 16 + i]);
    float p[16]; float sum = 0.f;
#pragma unroll
    for (int i = 0; i < 16; i++) { p[i] = __expf(s_aw[h * 16 + i] - mx); sum += p[i]; }
    float inv = 1.f / sum;

    int b = m / LQ;
    const float* vbase = Vt + ((size_t)b * NH + h) * LQ * DH;
    const int lvl_start[4] = {0, 4096, 5120, 5376};
    const int lvl_dim[4] = {64, 32, 16, 8};
    float acc = 0.f;
#pragma unroll
    for (int l = 0; l < 4; l++) {
        float rx = s_ref[l * 2 + 0], ry = s_ref[l * 2 + 1];
        int Wl = lvl_dim[l], Hl = lvl_dim[l];
        float fW = (float)Wl, fH = (float)Hl;
        int base = lvl_start[l];
#pragma unroll
        for (int k = 0; k < 4; k++) {
            int idx = l * 4 + k;
            float ox = s_off[(h * 16 + idx) * 2 + 0];
            float oy = s_off[(h * 16 + idx) * 2 + 1];
            float lx = rx + ox / fW, ly = ry + oy / fH;
            float x = lx * fW - 0.5f, y = ly * fH - 0.5f;
            float x0f = floorf(x), y0f = floorf(y);
            float wx = x - x0f, wy = y - y0f;
            int x0 = (int)x0f, y0 = (int)y0f;
            bool vx0 = (x0 >= 0) & (x0 < Wl);
            bool vx1 = (x0 + 1 >= 0) & (x0 + 1 < Wl);
            bool vy0 = (y0 >= 0) & (y0 < Hl);
            bool vy1 = (y0 + 1 >= 0) & (y0 + 1 < Hl);
            float v00 = 0.f, v01 = 0.f, v10 = 0.f, v11 = 0.f;
            if (vy0) {
                if (vx0) v00 = vbase[(size_t)(base + y0 * Wl + x0) * DH + d];
                if (vx1) v01 = vbase[(size_t)(base + y0 * Wl + x0 + 1) * DH + d];
            }
            if (vy1) {
                if (vx0) v10 = vbase[(size_t)(base + (y0 + 1) * Wl + x0) * DH + d];
                if (vx1) v11 = vbase[(size_t)(base + (y0 + 1) * Wl + x0 + 1) * DH + d];
            }
            float s = v00 * (1.f - wx) * (1.f - wy) + v01 * wx * (1.f - wy)
                    + v10 * (1.f - wx) * wy + v11 * wx * wy;
            acc += p[idx] * inv * s;
        }
    }
    attn_out[(size_t)m * 256 + tid] = acc;
}

// ---------------- stage D: output projection ----------------
__global__ __launch_bounds__(256) void k_out_proj(
    const float* __restrict__ X,    // (21760,256) attn_out
    const float* __restrict__ W,    // (256,256)
    const float* __restrict__ bias, // (256)
    float* __restrict__ Out)        // (21760,256)
{
    __shared__ float As[16][64];
    __shared__ float Bs[16][64];
    int tid = threadIdx.x;
    int m0 = blockIdx.x * 64, n0 = blockIdx.y * 64;
    int tx = tid & 15, ty = tid >> 4;
    float acc[4][4] = {};
    int lrow = tid >> 2;
    int lk4  = (tid & 3) * 4;
    const float* Ap = X + (size_t)(m0 + lrow) * 256 + lk4;
    const float* Bp = W + (size_t)(n0 + lrow) * 256 + lk4;
    for (int kc = 0; kc < 256; kc += 16) {
        float4 av = *(const float4*)(Ap + kc);
        float4 bv = *(const float4*)(Bp + kc);
        __syncthreads();
        As[lk4 + 0][lrow] = av.x; As[lk4 + 1][lrow] = av.y;
        As[lk4 + 2][lrow] = av.z; As[lk4 + 3][lrow] = av.w;
        Bs[lk4 + 0][lrow] = bv.x; Bs[lk4 + 1][lrow] = bv.y;
        Bs[lk4 + 2][lrow] = bv.z; Bs[lk4 + 3][lrow] = bv.w;
        __syncthreads();
#pragma unroll
        for (int kk = 0; kk < 16; kk++) {
            float a[4], b[4];
            *(float4*)a = *(const float4*)&As[kk][ty * 4];
            *(float4*)b = *(const float4*)&Bs[kk][tx * 4];
#pragma unroll
            for (int i = 0; i < 4; i++)
#pragma unroll
                for (int j = 0; j < 4; j++) acc[i][j] += a[i] * b[j];
        }
    }
#pragma unroll
    for (int i = 0; i < 4; i++) {
        int m = m0 + ty * 4 + i;
#pragma unroll
        for (int j = 0; j < 4; j++) {
            int n = n0 + tx * 4 + j;
            Out[(size_t)m * 256 + n] = acc[i][j] + bias[n];
        }
    }
}

// ---------------- launch ----------------
extern "C" void kernel_launch(void* const* d_in, const int* in_sizes, int n_in,
                              void* d_out, int out_size, void* d_ws, size_t ws_size,
                              hipStream_t stream) {
    const float* query  = (const float*)d_in[0];
    const float* refp   = (const float*)d_in[1];
    const float* inflat = (const float*)d_in[2];
    // d_in[3] = input_spatial_shapes (static, unused)
    const float* We  = (const float*)d_in[4];
    const float* SW  = (const float*)d_in[5];
    const float* SB  = (const float*)d_in[6];
    const float* AWw = (const float*)d_in[7];
    const float* ABb = (const float*)d_in[8];
    const float* VW  = (const float*)d_in[9];
    const float* Vb  = (const float*)d_in[10];
    const float* OW  = (const float*)d_in[11];
    const float* Ob  = (const float*)d_in[12];
    float* out = (float*)d_out;

    float* ws  = (float*)d_ws;
    float* Vt   = ws;                       // 5,570,560 floats
    float* offs = Vt + (size_t)MTOT * 256;  // 5,570,560
    float* awl  = offs + (size_t)MTOT * 256;// 2,785,280
    float* atn  = awl + (size_t)MTOT * 128; // 5,570,560

    k_value_proj<<<dim3(MTOT / 64, 4), 256, 0, stream>>>(inflat, VW, Vb, Vt);
    k_oe_fused<<<dim3(MTOT / 128, OEN / 128), 256, 0, stream>>>(
        query, We, SW, SB, AWw, ABb, offs, awl);
    k_sample<<<dim3(MTOT), 256, 0, stream>>>(Vt, refp, offs, awl, atn);
    k_out_proj<<<dim3(MTOT / 64, 4), 256, 0, stream>>>(atn, OW, Ob, out);
}

// Round 2
// 508.240 us; speedup vs baseline: 1.7655x; 1.7655x over previous
//
#include <hip/hip_runtime.h>
#include <hip/hip_bf16.h>

// ---------------- problem constants (static pyramid) ----------------
#define NB 4
#define LQ 5440
#define DM 256
#define NH 8
#define NL 4
#define NP 4
#define OFFD 32
#define DH 32
#define MTOT (NB * LQ)        // 21760
#define OEN (NH * NL * NP * OFFD)  // 4096
#define NGRP (NH * NL * NP)   // 128

typedef __attribute__((ext_vector_type(8))) short bf16x8;
typedef __attribute__((ext_vector_type(4))) float f32x4;
typedef unsigned int u32;

#define GLOAD_LDS16(gp, lp) \
    __builtin_amdgcn_global_load_lds((const __attribute__((address_space(1))) u32*)(gp), \
                                     (__attribute__((address_space(3))) u32*)(lp), 16, 0, 0)

// ---------------- fp32 -> bf16 conversion (vectorized) ----------------
__global__ __launch_bounds__(256) void k_cvt_bf16(
    const float* __restrict__ X, unsigned short* __restrict__ Y, int n4)
{
    int i = blockIdx.x * 256 + threadIdx.x;
    if (i < n4) {
        float4 v = *(const float4*)(X + (size_t)i * 4);
        __hip_bfloat16 h0 = __float2bfloat16(v.x);
        __hip_bfloat16 h1 = __float2bfloat16(v.y);
        __hip_bfloat16 h2 = __float2bfloat16(v.z);
        __hip_bfloat16 h3 = __float2bfloat16(v.w);
        ushort4 o;
        o.x = *(unsigned short*)&h0; o.y = *(unsigned short*)&h1;
        o.z = *(unsigned short*)&h2; o.w = *(unsigned short*)&h3;
        *(ushort4*)(Y + (size_t)i * 4) = o;
    }
}

// ---------------- stage A: value projection, transposed output ----------------
__global__ __launch_bounds__(256) void k_value_proj(
    const float* __restrict__ X,    // (21760,256)
    const float* __restrict__ W,    // (256,256) row-major (n,k)
    const float* __restrict__ bias, // (256)
    float* __restrict__ Vt)         // (4,8,5440,32)
{
    __shared__ float As[16][64];
    __shared__ float Bs[16][64];
    int tid = threadIdx.x;
    int m0 = blockIdx.x * 64, n0 = blockIdx.y * 64;
    int tx = tid & 15, ty = tid >> 4;
    float acc[4][4] = {};
    int lrow = tid >> 2;        // 0..63
    int lk4  = (tid & 3) * 4;   // 0,4,8,12
    const float* Ap = X + (size_t)(m0 + lrow) * 256 + lk4;
    const float* Bp = W + (size_t)(n0 + lrow) * 256 + lk4;
    for (int kc = 0; kc < 256; kc += 16) {
        float4 av = *(const float4*)(Ap + kc);
        float4 bv = *(const float4*)(Bp + kc);
        __syncthreads();
        As[lk4 + 0][lrow] = av.x; As[lk4 + 1][lrow] = av.y;
        As[lk4 + 2][lrow] = av.z; As[lk4 + 3][lrow] = av.w;
        Bs[lk4 + 0][lrow] = bv.x; Bs[lk4 + 1][lrow] = bv.y;
        Bs[lk4 + 2][lrow] = bv.z; Bs[lk4 + 3][lrow] = bv.w;
        __syncthreads();
#pragma unroll
        for (int kk = 0; kk < 16; kk++) {
            float a[4], b[4];
            *(float4*)a = *(const float4*)&As[kk][ty * 4];
            *(float4*)b = *(const float4*)&Bs[kk][tx * 4];
#pragma unroll
            for (int i = 0; i < 4; i++)
#pragma unroll
                for (int j = 0; j < 4; j++) acc[i][j] += a[i] * b[j];
        }
    }
#pragma unroll
    for (int i = 0; i < 4; i++) {
        int m = m0 + ty * 4 + i;
        int b = m / LQ, q = m % LQ;
#pragma unroll
        for (int j = 0; j < 4; j++) {
            int n = n0 + tx * 4 + j;
            int h = n >> 5, d = n & 31;
            Vt[(((size_t)b * NH + h) * LQ + q) * DH + d] = acc[i][j] + bias[n];
        }
    }
}

// ---------------- stage B: MFMA bf16 GEMM + silu + group reduction ----------------
// oe = silu(Q @ We^T) per-element; reduce groups of 32 cols against SW/AW.
// Layout facts (verified, guide §3): C/D 16x16 tile: col=lane&15, row=(lane>>4)*4+reg.
// A frag: A[m=lane&15][k=(lane>>4)*8+j]; B frag same pattern on (n,k)-major B.
__global__ __launch_bounds__(256) void k_oe_mfma(
    const unsigned short* __restrict__ Qb,   // (21760,256) bf16
    const unsigned short* __restrict__ Wb,   // (4096,256) bf16
    const float* __restrict__ SW,    // (128,32,2)
    const float* __restrict__ SB,    // (128,2)
    const float* __restrict__ AW,    // (128,32)
    const float* __restrict__ AB,    // (128)
    float* __restrict__ offs_out,    // (M,128,2)
    float* __restrict__ aw_out)      // (M,128)
{
    __shared__ short sA[128 * 32];   // [row][k] bf16
    __shared__ short sB[128 * 32];   // [col][k] bf16
    __shared__ float w0s[128], w1s[128], wAs[128];

    int tid = threadIdx.x;
    int m0 = blockIdx.x * 128, n0 = blockIdx.y * 128;

    if (tid < 128) {
        int n = n0 + tid;
        w0s[tid] = SW[n * 2 + 0];
        w1s[tid] = SW[n * 2 + 1];
        wAs[tid] = AW[n];
    }

    int lane = tid & 63;
    int w = tid >> 6;          // wave 0..3
    int wm = w >> 1, wn = w & 1;
    int lcol = lane & 15, lrow = lane >> 4;

    // staging: chunk c (16B) -> LDS row c>>2, k-quarter c&3. call0: c=tid, call1: c=tid+256
    const short* gA = (const short*)Qb + (size_t)(m0 + (tid >> 2)) * 256 + (tid & 3) * 8;
    const short* gB = (const short*)Wb + (size_t)(n0 + (tid >> 2)) * 256 + (tid & 3) * 8;
    const short* gA2 = gA + 64 * 256;
    const short* gB2 = gB + 64 * 256;
    short* lA = sA + w * 512;          // wave-uniform LDS base (bytes: w*1024)
    short* lB = sB + w * 512;

    f32x4 acc[4][4] = {};

    const short* pa = sA + (wm * 64 + lcol) * 32 + lrow * 8;
    const short* pb = sB + (wn * 64 + lcol) * 32 + lrow * 8;

    for (int kc = 0; kc < 256; kc += 32) {
        GLOAD_LDS16(gA + kc, lA);
        GLOAD_LDS16(gA2 + kc, lA + 2048);
        GLOAD_LDS16(gB + kc, lB);
        GLOAD_LDS16(gB2 + kc, lB + 2048);
        __syncthreads();
        bf16x8 a[4], b[4];
#pragma unroll
        for (int i = 0; i < 4; i++) a[i] = *(const bf16x8*)(pa + i * 16 * 32);
#pragma unroll
        for (int i = 0; i < 4; i++) b[i] = *(const bf16x8*)(pb + i * 16 * 32);
#pragma unroll
        for (int mi = 0; mi < 4; mi++)
#pragma unroll
            for (int ni = 0; ni < 4; ni++)
                acc[mi][ni] = __builtin_amdgcn_mfma_f32_16x16x32_bf16(
                    a[mi], b[ni], acc[mi][ni], 0, 0, 0);
        __syncthreads();
    }

    // epilogue: silu + weighted reduce over each 32-col group
#pragma unroll
    for (int mi = 0; mi < 4; mi++) {
#pragma unroll
        for (int g = 0; g < 2; g++) {
            float s0[4] = {0, 0, 0, 0}, s1[4] = {0, 0, 0, 0}, s2[4] = {0, 0, 0, 0};
#pragma unroll
            for (int t = 0; t < 2; t++) {
                int ni = g * 2 + t;
                int c = wn * 64 + ni * 16 + lcol;
                float w0v = w0s[c], w1v = w1s[c], wAv = wAs[c];
#pragma unroll
                for (int r = 0; r < 4; r++) {
                    float x = acc[mi][ni][r];
                    float su = x / (1.0f + __expf(-x));   // silu
                    s0[r] += su * w0v;
                    s1[r] += su * w1v;
                    s2[r] += su * wAv;
                }
            }
#pragma unroll
            for (int r = 0; r < 4; r++) {
#pragma unroll
                for (int off = 1; off < 16; off <<= 1) {
                    s0[r] += __shfl_xor(s0[r], off);
                    s1[r] += __shfl_xor(s1[r], off);
                    s2[r] += __shfl_xor(s2[r], off);
                }
            }
            if (lcol == 0) {
                int gg = (n0 + wn * 64 + g * 32) >> 5;
                float sb0 = SB[gg * 2 + 0], sb1 = SB[gg * 2 + 1], ab = AB[gg];
#pragma unroll
                for (int r = 0; r < 4; r++) {
                    int m = m0 + wm * 64 + mi * 16 + lrow * 4 + r;
                    size_t oi = ((size_t)m * NGRP + gg) * 2;
                    offs_out[oi + 0] = s0[r] + sb0;
                    offs_out[oi + 1] = s1[r] + sb1;
                    aw_out[(size_t)m * NGRP + gg] = s2[r] + ab;
                }
            }
        }
    }
}

// ---------------- stage C: softmax + bilinear sampling ----------------
__global__ __launch_bounds__(256) void k_sample(
    const float* __restrict__ Vt,    // (4,8,5440,32)
    const float* __restrict__ refp,  // (4,5440,4,2)
    const float* __restrict__ offs,  // (M,128,2)
    const float* __restrict__ awl,   // (M,128)
    float* __restrict__ attn_out)    // (M,256)
{
    int m = blockIdx.x;
    int tid = threadIdx.x;
    __shared__ float s_off[256];
    __shared__ float s_aw[128];
    __shared__ float s_ref[8];
    s_off[tid] = offs[(size_t)m * 256 + tid];
    if (tid < 128) s_aw[tid] = awl[(size_t)m * 128 + tid];
    if (tid < 8)   s_ref[tid] = refp[(size_t)m * 8 + tid];
    __syncthreads();

    int h = tid >> 5, d = tid & 31;
    float mx = -1e30f;
#pragma unroll
    for (int i = 0; i < 16; i++) mx = fmaxf(mx, s_aw[h * 16 + i]);
    float p[16]; float sum = 0.f;
#pragma unroll
    for (int i = 0; i < 16; i++) { p[i] = __expf(s_aw[h * 16 + i] - mx); sum += p[i]; }
    float inv = 1.f / sum;

    int b = m / LQ;
    const float* vbase = Vt + ((size_t)b * NH + h) * LQ * DH;
    const int lvl_start[4] = {0, 4096, 5120, 5376};
    const int lvl_dim[4] = {64, 32, 16, 8};
    float acc = 0.f;
#pragma unroll
    for (int l = 0; l < 4; l++) {
        float rx = s_ref[l * 2 + 0], ry = s_ref[l * 2 + 1];
        int Wl = lvl_dim[l], Hl = lvl_dim[l];
        float fW = (float)Wl, fH = (float)Hl;
        int base = lvl_start[l];
#pragma unroll
        for (int k = 0; k < 4; k++) {
            int idx = l * 4 + k;
            float ox = s_off[(h * 16 + idx) * 2 + 0];
            float oy = s_off[(h * 16 + idx) * 2 + 1];
            float lx = rx + ox / fW, ly = ry + oy / fH;
            float x = lx * fW - 0.5f, y = ly * fH - 0.5f;
            float x0f = floorf(x), y0f = floorf(y);
            float wx = x - x0f, wy = y - y0f;
            int x0 = (int)x0f, y0 = (int)y0f;
            bool vx0 = (x0 >= 0) & (x0 < Wl);
            bool vx1 = (x0 + 1 >= 0) & (x0 + 1 < Wl);
            bool vy0 = (y0 >= 0) & (y0 < Hl);
            bool vy1 = (y0 + 1 >= 0) & (y0 + 1 < Hl);
            float v00 = 0.f, v01 = 0.f, v10 = 0.f, v11 = 0.f;
            if (vy0) {
                if (vx0) v00 = vbase[(size_t)(base + y0 * Wl + x0) * DH + d];
                if (vx1) v01 = vbase[(size_t)(base + y0 * Wl + x0 + 1) * DH + d];
            }
            if (vy1) {
                if (vx0) v10 = vbase[(size_t)(base + (y0 + 1) * Wl + x0) * DH + d];
                if (vx1) v11 = vbase[(size_t)(base + (y0 + 1) * Wl + x0 + 1) * DH + d];
            }
            float s = v00 * (1.f - wx) * (1.f - wy) + v01 * wx * (1.f - wy)
                    + v10 * (1.f - wx) * wy + v11 * wx * wy;
            acc += p[idx] * inv * s;
        }
    }
    attn_out[(size_t)m * 256 + tid] = acc;
}

// ---------------- stage D: output projection ----------------
__global__ __launch_bounds__(256) void k_out_proj(
    const float* __restrict__ X,    // (21760,256) attn_out
    const float* __restrict__ W,    // (256,256)
    const float* __restrict__ bias, // (256)
    float* __restrict__ Out)        // (21760,256)
{
    __shared__ float As[16][64];
    __shared__ float Bs[16][64];
    int tid = threadIdx.x;
    int m0 = blockIdx.x * 64, n0 = blockIdx.y * 64;
    int tx = tid & 15, ty = tid >> 4;
    float acc[4][4] = {};
    int lrow = tid >> 2;
    int lk4  = (tid & 3) * 4;
    const float* Ap = X + (size_t)(m0 + lrow) * 256 + lk4;
    const float* Bp = W + (size_t)(n0 + lrow) * 256 + lk4;
    for (int kc = 0; kc < 256; kc += 16) {
        float4 av = *(const float4*)(Ap + kc);
        float4 bv = *(const float4*)(Bp + kc);
        __syncthreads();
        As[lk4 + 0][lrow] = av.x; As[lk4 + 1][lrow] = av.y;
        As[lk4 + 2][lrow] = av.z; As[lk4 + 3][lrow] = av.w;
        Bs[lk4 + 0][lrow] = bv.x; Bs[lk4 + 1][lrow] = bv.y;
        Bs[lk4 + 2][lrow] = bv.z; Bs[lk4 + 3][lrow] = bv.w;
        __syncthreads();
#pragma unroll
        for (int kk = 0; kk < 16; kk++) {
            float a[4], b[4];
            *(float4*)a = *(const float4*)&As[kk][ty * 4];
            *(float4*)b = *(const float4*)&Bs[kk][tx * 4];
#pragma unroll
            for (int i = 0; i < 4; i++)
#pragma unroll
                for (int j = 0; j < 4; j++) acc[i][j] += a[i] * b[j];
        }
    }
#pragma unroll
    for (int i = 0; i < 4; i++) {
        int m = m0 + ty * 4 + i;
#pragma unroll
        for (int j = 0; j < 4; j++) {
            int n = n0 + tx * 4 + j;
            Out[(size_t)m * 256 + n] = acc[i][j] + bias[n];
        }
    }
}

// ---------------- launch ----------------
extern "C" void kernel_launch(void* const* d_in, const int* in_sizes, int n_in,
                              void* d_out, int out_size, void* d_ws, size_t ws_size,
                              hipStream_t stream) {
    const float* query  = (const float*)d_in[0];
    const float* refp   = (const float*)d_in[1];
    const float* inflat = (const float*)d_in[2];
    // d_in[3] = input_spatial_shapes (static, unused)
    const float* We  = (const float*)d_in[4];
    const float* SW  = (const float*)d_in[5];
    const float* SB  = (const float*)d_in[6];
    const float* AWw = (const float*)d_in[7];
    const float* ABb = (const float*)d_in[8];
    const float* VW  = (const float*)d_in[9];
    const float* Vb  = (const float*)d_in[10];
    const float* OW  = (const float*)d_in[11];
    const float* Ob  = (const float*)d_in[12];
    float* out = (float*)d_out;

    float* ws  = (float*)d_ws;
    float* Vt   = ws;                       // 5,570,560 floats
    float* offs = Vt + (size_t)MTOT * 256;  // 5,570,560
    float* awl  = offs + (size_t)MTOT * 256;// 2,785,280
    float* atn  = awl + (size_t)MTOT * 128; // 5,570,560
    // bf16 staging aliases the atn region (atn written only later by k_sample)
    unsigned short* Qbf = (unsigned short*)atn;                 // 5,570,560 bf16
    unsigned short* Webf = Qbf + (size_t)MTOT * 256;            // 1,048,576 bf16

    k_cvt_bf16<<<dim3((MTOT * 256 / 4 + 255) / 256), 256, 0, stream>>>(query, Qbf, MTOT * 256 / 4);
    k_cvt_bf16<<<dim3((OEN * 256 / 4 + 255) / 256), 256, 0, stream>>>(We, Webf, OEN * 256 / 4);

    k_value_proj<<<dim3(MTOT / 64, 4), 256, 0, stream>>>(inflat, VW, Vb, Vt);

    k_oe_mfma<<<dim3(MTOT / 128, OEN / 128), 256, 0, stream>>>(
        Qbf, Webf, SW, SB, AWw, ABb, offs, awl);

    k_sample<<<dim3(MTOT), 256, 0, stream>>>(Vt, refp, offs, awl, atn);
    k_out_proj<<<dim3(MTOT / 64, 4), 256, 0, stream>>>(atn, OW, Ob, out);
}

// Round 3
// 353.348 us; speedup vs baseline: 2.5394x; 1.4384x over previous
//
#include <hip/hip_runtime.h>
#include <hip/hip_bf16.h>

// ---------------- problem constants (static pyramid) ----------------
#define NB 4
#define LQ 5440
#define DM 256
#define NH 8
#define NL 4
#define NP 4
#define OFFD 32
#define DH 32
#define MTOT (NB * LQ)             // 21760
#define OEN (NH * NL * NP * OFFD)  // 4096
#define NGRP (NH * NL * NP)        // 128

typedef __attribute__((ext_vector_type(8))) short bf16x8;
typedef __attribute__((ext_vector_type(4))) float f32x4;
typedef unsigned int u32;

#define GLOAD_LDS16(gp, lp) \
    __builtin_amdgcn_global_load_lds((const __attribute__((address_space(1))) u32*)(gp), \
                                     (__attribute__((address_space(3))) u32*)(lp), 16, 0, 0)

__device__ __forceinline__ float bf2f(unsigned short u) {
    union { unsigned int i; float f; } v; v.i = ((unsigned int)u) << 16; return v.f;
}
__device__ __forceinline__ unsigned short f2bf(float x) {
    __hip_bfloat16 h = __float2bfloat16(x);
    return *(unsigned short*)&h;
}

// ---------------- fp32 -> bf16 conversions ----------------
// two equal-size big tensors (query, input_flatten)
__global__ __launch_bounds__(256) void k_cvt2(
    const float* __restrict__ A, unsigned short* __restrict__ Ao,
    const float* __restrict__ B, unsigned short* __restrict__ Bo, int n4)
{
    int i = blockIdx.x * 256 + threadIdx.x;
    if (i >= n4) return;
    const float* src = blockIdx.y ? B : A;
    unsigned short* dst = blockIdx.y ? Bo : Ao;
    float4 v = *(const float4*)(src + (size_t)i * 4);
    ushort4 o;
    o.x = f2bf(v.x); o.y = f2bf(v.y); o.z = f2bf(v.z); o.w = f2bf(v.w);
    *(ushort4*)(dst + (size_t)i * 4) = o;
}
// three weight tensors (We, value_W, out_W)
__global__ __launch_bounds__(256) void k_cvt3(
    const float* __restrict__ A, unsigned short* __restrict__ Ao, int nA4,
    const float* __restrict__ B, unsigned short* __restrict__ Bo, int nB4,
    const float* __restrict__ C, unsigned short* __restrict__ Co, int nC4)
{
    int i = blockIdx.x * 256 + threadIdx.x;
    const float* src; unsigned short* dst; int n4;
    if (blockIdx.y == 0)      { src = A; dst = Ao; n4 = nA4; }
    else if (blockIdx.y == 1) { src = B; dst = Bo; n4 = nB4; }
    else                      { src = C; dst = Co; n4 = nC4; }
    if (i >= n4) return;
    float4 v = *(const float4*)(src + (size_t)i * 4);
    ushort4 o;
    o.x = f2bf(v.x); o.y = f2bf(v.y); o.z = f2bf(v.z); o.w = f2bf(v.w);
    *(ushort4*)(dst + (size_t)i * 4) = o;
}

// ============================================================================
// Shared MFMA GEMM skeleton: 128x128 tile, BK=64, XOR-swizzled LDS staging.
// Staging: chunk c (16B) at LDS slot (row=c>>3, q=c&7) holds GLOBAL chunk
// (row, q ^ (row&7)).  Reader of global chunk (row, kq) reads slot
// (row, kq ^ (row&7)) -> conflict-free ds_read_b128 across lcol lanes.
// C/D layout (verified): col = lane&15, row = (lane>>4)*4 + reg.
// ============================================================================

// ---------------- stage B: MFMA bf16 GEMM + silu + group reduction ----------------
__global__ __launch_bounds__(256) void k_oe_mfma(
    const unsigned short* __restrict__ Qb,   // (21760,256) bf16
    const unsigned short* __restrict__ Wb,   // (4096,256) bf16
    const float* __restrict__ SW,    // (128,32,2)
    const float* __restrict__ SB,    // (128,2)
    const float* __restrict__ AW,    // (128,32)
    const float* __restrict__ AB,    // (128)
    float* __restrict__ offs_out,    // (M,128,2)
    float* __restrict__ aw_out)      // (M,128)
{
    __shared__ short sA[128 * 64];
    __shared__ short sB[128 * 64];
    __shared__ float w0s[128], w1s[128], wAs[128];

    int tid = threadIdx.x;
    int n0 = blockIdx.x * 128;   // n fastest-varying -> concurrent blocks share Q via L2
    int m0 = blockIdx.y * 128;

    if (tid < 128) {
        int n = n0 + tid;
        w0s[tid] = SW[n * 2 + 0];
        w1s[tid] = SW[n * 2 + 1];
        wAs[tid] = AW[n];
    }

    int lane = tid & 63;
    int w = tid >> 6;
    int wm = w >> 1, wn = w & 1;
    int lcol = lane & 15, lrow = lane >> 4;

    // staging addresses (global source XOR-permuted)
    int srow = tid >> 3;
    int sq = (tid & 7) ^ (srow & 7);
    const short* gA = (const short*)Qb + (size_t)(m0 + srow) * 256 + sq * 8;
    const short* gB = (const short*)Wb + (size_t)(n0 + srow) * 256 + sq * 8;
    short* lA = sA + w * 512;
    short* lB = sB + w * 512;

    f32x4 acc[4][4] = {};

    const short* pa = sA + (wm * 64 + lcol) * 64;
    const short* pb = sB + (wn * 64 + lcol) * 64;
    int rx7 = lcol & 7;
    int qa0 = (lrow ^ rx7) * 8;        // kh=0 slot offset (shorts)
    int qa1 = ((4 + lrow) ^ rx7) * 8;  // kh=1

    for (int kc = 0; kc < 256; kc += 64) {
#pragma unroll
        for (int j = 0; j < 4; j++) {
            GLOAD_LDS16(gA + kc + j * 32 * 256, lA + j * 2048);
            GLOAD_LDS16(gB + kc + j * 32 * 256, lB + j * 2048);
        }
        __syncthreads();
        bf16x8 a[4][2], b[4][2];
#pragma unroll
        for (int i = 0; i < 4; i++) {
            a[i][0] = *(const bf16x8*)(pa + i * 16 * 64 + qa0);
            a[i][1] = *(const bf16x8*)(pa + i * 16 * 64 + qa1);
            b[i][0] = *(const bf16x8*)(pb + i * 16 * 64 + qa0);
            b[i][1] = *(const bf16x8*)(pb + i * 16 * 64 + qa1);
        }
#pragma unroll
        for (int kh = 0; kh < 2; kh++)
#pragma unroll
            for (int mi = 0; mi < 4; mi++)
#pragma unroll
                for (int ni = 0; ni < 4; ni++)
                    acc[mi][ni] = __builtin_amdgcn_mfma_f32_16x16x32_bf16(
                        a[mi][kh], b[ni][kh], acc[mi][ni], 0, 0, 0);
        __syncthreads();
    }

    // epilogue: silu + weighted reduce over each 32-col group
#pragma unroll
    for (int mi = 0; mi < 4; mi++) {
#pragma unroll
        for (int g = 0; g < 2; g++) {
            float s0[4] = {0, 0, 0, 0}, s1[4] = {0, 0, 0, 0}, s2[4] = {0, 0, 0, 0};
#pragma unroll
            for (int t = 0; t < 2; t++) {
                int ni = g * 2 + t;
                int c = wn * 64 + ni * 16 + lcol;
                float w0v = w0s[c], w1v = w1s[c], wAv = wAs[c];
#pragma unroll
                for (int r = 0; r < 4; r++) {
                    float x = acc[mi][ni][r];
                    float su = x / (1.0f + __expf(-x));   // silu
                    s0[r] += su * w0v;
                    s1[r] += su * w1v;
                    s2[r] += su * wAv;
                }
            }
#pragma unroll
            for (int r = 0; r < 4; r++) {
#pragma unroll
                for (int off = 1; off < 16; off <<= 1) {
                    s0[r] += __shfl_xor(s0[r], off);
                    s1[r] += __shfl_xor(s1[r], off);
                    s2[r] += __shfl_xor(s2[r], off);
                }
            }
            if (lcol == 0) {
                int gg = (n0 + wn * 64 + g * 32) >> 5;
                float sb0 = SB[gg * 2 + 0], sb1 = SB[gg * 2 + 1], ab = AB[gg];
#pragma unroll
                for (int r = 0; r < 4; r++) {
                    int m = m0 + wm * 64 + mi * 16 + lrow * 4 + r;
                    size_t oi = ((size_t)m * NGRP + gg) * 2;
                    offs_out[oi + 0] = s0[r] + sb0;
                    offs_out[oi + 1] = s1[r] + sb1;
                    aw_out[(size_t)m * NGRP + gg] = s2[r] + ab;
                }
            }
        }
    }
}

// ---------------- stage A: value projection (bf16 MFMA) -> Vt bf16 transposed ----------------
__global__ __launch_bounds__(256) void k_value_mfma(
    const unsigned short* __restrict__ Xb,   // (21760,256) bf16
    const unsigned short* __restrict__ Wvb,  // (256,256) bf16 (n,k)
    const float* __restrict__ bias,          // (256)
    unsigned short* __restrict__ Vtb)        // (4,8,5440,32) bf16
{
    __shared__ short sA[128 * 64];
    __shared__ short sB[128 * 64];
    int tid = threadIdx.x;
    int n0 = blockIdx.x * 128;
    int m0 = blockIdx.y * 128;
    int lane = tid & 63;
    int w = tid >> 6;
    int wm = w >> 1, wn = w & 1;
    int lcol = lane & 15, lrow = lane >> 4;

    int srow = tid >> 3;
    int sq = (tid & 7) ^ (srow & 7);
    const short* gA = (const short*)Xb + (size_t)(m0 + srow) * 256 + sq * 8;
    const short* gB = (const short*)Wvb + (size_t)(n0 + srow) * 256 + sq * 8;
    short* lA = sA + w * 512;
    short* lB = sB + w * 512;

    f32x4 acc[4][4] = {};
    const short* pa = sA + (wm * 64 + lcol) * 64;
    const short* pb = sB + (wn * 64 + lcol) * 64;
    int rx7 = lcol & 7;
    int qa0 = (lrow ^ rx7) * 8;
    int qa1 = ((4 + lrow) ^ rx7) * 8;

    for (int kc = 0; kc < 256; kc += 64) {
#pragma unroll
        for (int j = 0; j < 4; j++) {
            GLOAD_LDS16(gA + kc + j * 32 * 256, lA + j * 2048);
            GLOAD_LDS16(gB + kc + j * 32 * 256, lB + j * 2048);
        }
        __syncthreads();
        bf16x8 a[4][2], b[4][2];
#pragma unroll
        for (int i = 0; i < 4; i++) {
            a[i][0] = *(const bf16x8*)(pa + i * 16 * 64 + qa0);
            a[i][1] = *(const bf16x8*)(pa + i * 16 * 64 + qa1);
            b[i][0] = *(const bf16x8*)(pb + i * 16 * 64 + qa0);
            b[i][1] = *(const bf16x8*)(pb + i * 16 * 64 + qa1);
        }
#pragma unroll
        for (int kh = 0; kh < 2; kh++)
#pragma unroll
            for (int mi = 0; mi < 4; mi++)
#pragma unroll
                for (int ni = 0; ni < 4; ni++)
                    acc[mi][ni] = __builtin_amdgcn_mfma_f32_16x16x32_bf16(
                        a[mi][kh], b[ni][kh], acc[mi][ni], 0, 0, 0);
        __syncthreads();
    }

#pragma unroll
    for (int mi = 0; mi < 4; mi++) {
#pragma unroll
        for (int ni = 0; ni < 4; ni++) {
            int n = n0 + wn * 64 + ni * 16 + lcol;
            int h = n >> 5, d = n & 31;
            float bn = bias[n];
#pragma unroll
            for (int r = 0; r < 4; r++) {
                int m = m0 + wm * 64 + mi * 16 + lrow * 4 + r;
                int b = m / LQ, q = m - b * LQ;
                Vtb[(((size_t)b * NH + h) * LQ + q) * DH + d] = f2bf(acc[mi][ni][r] + bn);
            }
        }
    }
}

// ---------------- stage D: output projection (bf16 MFMA) ----------------
__global__ __launch_bounds__(256) void k_out_mfma(
    const unsigned short* __restrict__ Xb,   // (21760,256) bf16 attn
    const unsigned short* __restrict__ Wob,  // (256,256) bf16 (n,k)
    const float* __restrict__ bias,          // (256)
    float* __restrict__ Out)                 // (21760,256) fp32
{
    __shared__ short sA[128 * 64];
    __shared__ short sB[128 * 64];
    int tid = threadIdx.x;
    int n0 = blockIdx.x * 128;
    int m0 = blockIdx.y * 128;
    int lane = tid & 63;
    int w = tid >> 6;
    int wm = w >> 1, wn = w & 1;
    int lcol = lane & 15, lrow = lane >> 4;

    int srow = tid >> 3;
    int sq = (tid & 7) ^ (srow & 7);
    const short* gA = (const short*)Xb + (size_t)(m0 + srow) * 256 + sq * 8;
    const short* gB = (const short*)Wob + (size_t)(n0 + srow) * 256 + sq * 8;
    short* lA = sA + w * 512;
    short* lB = sB + w * 512;

    f32x4 acc[4][4] = {};
    const short* pa = sA + (wm * 64 + lcol) * 64;
    const short* pb = sB + (wn * 64 + lcol) * 64;
    int rx7 = lcol & 7;
    int qa0 = (lrow ^ rx7) * 8;
    int qa1 = ((4 + lrow) ^ rx7) * 8;

    for (int kc = 0; kc < 256; kc += 64) {
#pragma unroll
        for (int j = 0; j < 4; j++) {
            GLOAD_LDS16(gA + kc + j * 32 * 256, lA + j * 2048);
            GLOAD_LDS16(gB + kc + j * 32 * 256, lB + j * 2048);
        }
        __syncthreads();
        bf16x8 a[4][2], b[4][2];
#pragma unroll
        for (int i = 0; i < 4; i++) {
            a[i][0] = *(const bf16x8*)(pa + i * 16 * 64 + qa0);
            a[i][1] = *(const bf16x8*)(pa + i * 16 * 64 + qa1);
            b[i][0] = *(const bf16x8*)(pb + i * 16 * 64 + qa0);
            b[i][1] = *(const bf16x8*)(pb + i * 16 * 64 + qa1);
        }
#pragma unroll
        for (int kh = 0; kh < 2; kh++)
#pragma unroll
            for (int mi = 0; mi < 4; mi++)
#pragma unroll
                for (int ni = 0; ni < 4; ni++)
                    acc[mi][ni] = __builtin_amdgcn_mfma_f32_16x16x32_bf16(
                        a[mi][kh], b[ni][kh], acc[mi][ni], 0, 0, 0);
        __syncthreads();
    }

#pragma unroll
    for (int mi = 0; mi < 4; mi++) {
#pragma unroll
        for (int ni = 0; ni < 4; ni++) {
            int n = n0 + wn * 64 + ni * 16 + lcol;
            float bn = bias[n];
#pragma unroll
            for (int r = 0; r < 4; r++) {
                int m = m0 + wm * 64 + mi * 16 + lrow * 4 + r;
                Out[(size_t)m * 256 + n] = acc[mi][ni][r] + bn;
            }
        }
    }
}

// ---------------- stage C: softmax + bilinear sampling (prep-in-LDS) ----------------
__global__ __launch_bounds__(256) void k_sample(
    const unsigned short* __restrict__ Vtb,  // (4,8,5440,32) bf16
    const float* __restrict__ refp,          // (4,5440,4,2)
    const float* __restrict__ offs,          // (M,128,2)
    const float* __restrict__ awl,           // (M,128)
    unsigned short* __restrict__ atnb)       // (M,256) bf16
{
    int m = blockIdx.x;
    int tid = threadIdx.x;
    __shared__ int   s_idx[128][4];
    __shared__ float s_w[128][4];

    if (tid < 128) {
        int p = tid;                    // (h,l,k) point id
        int l = (p >> 2) & 3;
        // softmax over the 16-point group (lanes p&~15 .. |15, within one wave)
        float logit = awl[(size_t)m * 128 + p];
        float mx = logit;
#pragma unroll
        for (int off = 1; off < 16; off <<= 1) mx = fmaxf(mx, __shfl_xor(mx, off));
        float e = __expf(logit - mx);
        float s = e;
#pragma unroll
        for (int off = 1; off < 16; off <<= 1) s += __shfl_xor(s, off);
        float prob = e / s;

        float ox = offs[((size_t)m * 128 + p) * 2 + 0];
        float oy = offs[((size_t)m * 128 + p) * 2 + 1];
        float rx = refp[(size_t)m * 8 + l * 2 + 0];
        float ry = refp[(size_t)m * 8 + l * 2 + 1];
        int Wl = 64 >> l;
        int base = (l == 0) ? 0 : (l == 1) ? 4096 : (l == 2) ? 5120 : 5376;
        float fW = (float)Wl;
        float x = rx * fW + ox - 0.5f;
        float y = ry * fW + oy - 0.5f;
        float x0f = floorf(x), y0f = floorf(y);
        float wx = x - x0f, wy = y - y0f;
        int x0 = (int)x0f, y0 = (int)y0f;
        int xc0 = min(max(x0, 0), Wl - 1), xc1 = min(max(x0 + 1, 0), Wl - 1);
        int yc0 = min(max(y0, 0), Wl - 1), yc1 = min(max(y0 + 1, 0), Wl - 1);
        float vx0 = (x0 >= 0 && x0 < Wl) ? 1.f : 0.f;
        float vx1 = (x0 + 1 >= 0 && x0 + 1 < Wl) ? 1.f : 0.f;
        float vy0 = (y0 >= 0 && y0 < Wl) ? 1.f : 0.f;
        float vy1 = (y0 + 1 >= 0 && y0 + 1 < Wl) ? 1.f : 0.f;
        s_idx[p][0] = (base + yc0 * Wl + xc0) * DH;
        s_idx[p][1] = (base + yc0 * Wl + xc1) * DH;
        s_idx[p][2] = (base + yc1 * Wl + xc0) * DH;
        s_idx[p][3] = (base + yc1 * Wl + xc1) * DH;
        s_w[p][0] = prob * (1.f - wx) * (1.f - wy) * vx0 * vy0;
        s_w[p][1] = prob * wx * (1.f - wy) * vx1 * vy0;
        s_w[p][2] = prob * (1.f - wx) * wy * vx0 * vy1;
        s_w[p][3] = prob * wx * wy * vx1 * vy1;
    }
    __syncthreads();

    int h = tid >> 5, d = tid & 31;
    int b = m / LQ;
    const unsigned short* vb = Vtb + ((size_t)b * NH + h) * LQ * DH + d;
    float acc = 0.f;
#pragma unroll
    for (int p16 = 0; p16 < 16; p16++) {
        int p = h * 16 + p16;
        int4 ri = *(const int4*)s_idx[p];
        float4 wv = *(const float4*)s_w[p];
        float v00 = bf2f(vb[ri.x]);
        float v01 = bf2f(vb[ri.y]);
        float v10 = bf2f(vb[ri.z]);
        float v11 = bf2f(vb[ri.w]);
        acc += wv.x * v00 + wv.y * v01 + wv.z * v10 + wv.w * v11;
    }
    atnb[(size_t)m * 256 + tid] = f2bf(acc);
}

// ---------------- launch ----------------
extern "C" void kernel_launch(void* const* d_in, const int* in_sizes, int n_in,
                              void* d_out, int out_size, void* d_ws, size_t ws_size,
                              hipStream_t stream) {
    const float* query  = (const float*)d_in[0];
    const float* refp   = (const float*)d_in[1];
    const float* inflat = (const float*)d_in[2];
    // d_in[3] = input_spatial_shapes (static, unused)
    const float* We  = (const float*)d_in[4];
    const float* SW  = (const float*)d_in[5];
    const float* SB  = (const float*)d_in[6];
    const float* AWw = (const float*)d_in[7];
    const float* ABb = (const float*)d_in[8];
    const float* VW  = (const float*)d_in[9];
    const float* Vb  = (const float*)d_in[10];
    const float* OW  = (const float*)d_in[11];
    const float* Ob  = (const float*)d_in[12];
    float* out = (float*)d_out;

    // workspace layout (floats): total ~17.3M floats = 69 MB
    float* ws = (float*)d_ws;
    unsigned short* Vtb  = (unsigned short*)ws;                    // 5,570,560 shorts
    float* offs          = ws + 2785280;                           // 5,570,560 f
    float* awl           = offs + 5570560;                         // 2,785,280 f
    unsigned short* Qbf  = (unsigned short*)(awl + 2785280);       // 5,570,560 shorts
    unsigned short* Webf = Qbf + 5570560;                          // 1,048,576 shorts
    unsigned short* Xbf  = Webf + 1048576;                         // 5,570,560 shorts (aliased: atnb after k_value_mfma)
    unsigned short* Wvbf = Xbf + 5570560;                          // 65,536 shorts
    unsigned short* OWbf = Wvbf + 65536;                           // 65,536 shorts
    unsigned short* atnb = Xbf;   // alias: Xb consumed by k_value_mfma before k_sample writes

    k_cvt2<<<dim3(5440, 2), 256, 0, stream>>>(query, Qbf, inflat, Xbf, MTOT * 256 / 4);
    k_cvt3<<<dim3(1024, 3), 256, 0, stream>>>(We, Webf, OEN * 256 / 4,
                                              VW, Wvbf, 256 * 256 / 4,
                                              OW, OWbf, 256 * 256 / 4);

    k_value_mfma<<<dim3(2, MTOT / 128), 256, 0, stream>>>(Xbf, Wvbf, Vb, Vtb);

    k_oe_mfma<<<dim3(OEN / 128, MTOT / 128), 256, 0, stream>>>(
        Qbf, Webf, SW, SB, AWw, ABb, offs, awl);

    k_sample<<<dim3(MTOT), 256, 0, stream>>>(Vtb, refp, offs, awl, atnb);

    k_out_mfma<<<dim3(2, MTOT / 128), 256, 0, stream>>>(atnb, OWbf, Ob, out);
}

// Round 4
// 288.528 us; speedup vs baseline: 3.1099x; 1.2247x over previous
//
#include <hip/hip_runtime.h>
#include <hip/hip_bf16.h>

// ---------------- problem constants (static pyramid) ----------------
#define NB 4
#define LQ 5440
#define DM 256
#define NH 8
#define NL 4
#define NP 4
#define OFFD 32
#define DH 32
#define MTOT (NB * LQ)             // 21760
#define OEN (NH * NL * NP * OFFD)  // 4096
#define NGRP (NH * NL * NP)        // 128

typedef __attribute__((ext_vector_type(8))) short bf16x8;
typedef __attribute__((ext_vector_type(4))) float f32x4;
typedef unsigned int u32;

#define GLOAD_LDS16(gp, lp) \
    __builtin_amdgcn_global_load_lds((const __attribute__((address_space(1))) u32*)(gp), \
                                     (__attribute__((address_space(3))) u32*)(lp), 16, 0, 0)

__device__ __forceinline__ float bf2f(unsigned short u) {
    union { unsigned int i; float f; } v; v.i = ((unsigned int)u) << 16; return v.f;
}
__device__ __forceinline__ unsigned short f2bf(float x) {
    __hip_bfloat16 h = __float2bfloat16(x);
    return *(unsigned short*)&h;
}
__device__ __forceinline__ u32 pk2(float a, float b) {
    return (u32)f2bf(a) | ((u32)f2bf(b) << 16);
}
__device__ __forceinline__ float silu(float x) {
    return x / (1.0f + __expf(-x));
}

// ---------------- fp32 -> bf16 conversions ----------------
__global__ __launch_bounds__(256) void k_cvt2(
    const float* __restrict__ A, unsigned short* __restrict__ Ao,
    const float* __restrict__ B, unsigned short* __restrict__ Bo, int n4)
{
    int i = blockIdx.x * 256 + threadIdx.x;
    if (i >= n4) return;
    const float* src = blockIdx.y ? B : A;
    unsigned short* dst = blockIdx.y ? Bo : Ao;
    float4 v = *(const float4*)(src + (size_t)i * 4);
    ushort4 o;
    o.x = f2bf(v.x); o.y = f2bf(v.y); o.z = f2bf(v.z); o.w = f2bf(v.w);
    *(ushort4*)(dst + (size_t)i * 4) = o;
}
__global__ __launch_bounds__(256) void k_cvt3(
    const float* __restrict__ A, unsigned short* __restrict__ Ao, int nA4,
    const float* __restrict__ B, unsigned short* __restrict__ Bo, int nB4,
    const float* __restrict__ C, unsigned short* __restrict__ Co, int nC4)
{
    int i = blockIdx.x * 256 + threadIdx.x;
    const float* src; unsigned short* dst; int n4;
    if (blockIdx.y == 0)      { src = A; dst = Ao; n4 = nA4; }
    else if (blockIdx.y == 1) { src = B; dst = Bo; n4 = nB4; }
    else                      { src = C; dst = Co; n4 = nC4; }
    if (i >= n4) return;
    float4 v = *(const float4*)(src + (size_t)i * 4);
    ushort4 o;
    o.x = f2bf(v.x); o.y = f2bf(v.y); o.z = f2bf(v.z); o.w = f2bf(v.w);
    *(ushort4*)(dst + (size_t)i * 4) = o;
}

// ---------------- prepack reduction weights: Rb[gg][j16][d32] bf16 ----------------
// j=0: SW[gg][d][0], j=1: SW[gg][d][1], j=2: AW[gg][d], j>=3: 0
__global__ __launch_bounds__(256) void k_prep_r(
    const float* __restrict__ SW, const float* __restrict__ AW,
    unsigned short* __restrict__ Rb)
{
    int idx = blockIdx.x * 256 + threadIdx.x;   // 65536 total
    int gg = idx >> 9, jo = (idx >> 5) & 15, d = idx & 31;
    float v = 0.f;
    if (jo == 0)      v = SW[(gg * 32 + d) * 2 + 0];
    else if (jo == 1) v = SW[(gg * 32 + d) * 2 + 1];
    else if (jo == 2) v = AW[gg * 32 + d];
    Rb[idx] = f2bf(v);
}

// ============================================================================
// Stage B: MFMA bf16 GEMM (operands swapped: A=We, B=Q -> acc is n-major) +
// silu + MFMA-based group reduction (no butterfly shuffles).
// Staging XOR swizzle: chunk c (16B) at LDS slot (row=c>>3, q=c&7) holds
// GLOBAL chunk (row, q ^ (row&7)); reader of (row,kq) reads slot kq^(row&7).
// C/D layout (verified): col(n_mfma) = lane&15, row(m_mfma) = (lane>>4)*4+reg.
// ============================================================================
__global__ __launch_bounds__(256) void k_oe_mfma(
    const unsigned short* __restrict__ Qb,   // (21760,256) bf16
    const unsigned short* __restrict__ Wb,   // (4096,256) bf16
    const unsigned short* __restrict__ Rb,   // (128,16,32) bf16 reduction frags
    const float* __restrict__ SB,    // (128,2)
    const float* __restrict__ AB,    // (128)
    float* __restrict__ offs_out,    // (M,128,2)
    float* __restrict__ aw_out)      // (M,128)
{
    __shared__ short sA[128 * 64];   // Q rows
    __shared__ short sB[128 * 64];   // We rows
    int tid = threadIdx.x;
    int n0 = blockIdx.x * 128;   // We/n fastest-varying -> blocks share Q via L2
    int m0 = blockIdx.y * 128;

    int lane = tid & 63;
    int w = tid >> 6;
    int wA = w >> 1;            // We half (mfma-m)
    int wB = w & 1;             // Q half (mfma-n)
    int lcol = lane & 15, quad = lane >> 4;

    int srow = tid >> 3;
    int sq = (tid & 7) ^ (srow & 7);
    const short* gA = (const short*)Qb + (size_t)(m0 + srow) * 256 + sq * 8;
    const short* gB = (const short*)Wb + (size_t)(n0 + srow) * 256 + sq * 8;
    short* lA = sA + w * 512;
    short* lB = sB + w * 512;

    f32x4 acc[4][4] = {};   // [We-tile i][Q-tile j]

    const short* pq = sA + (wB * 64 + lcol) * 64;   // Q fragments (B operand)
    const short* pw = sB + (wA * 64 + lcol) * 64;   // We fragments (A operand)
    int rx7 = lcol & 7;
    int qa0 = (quad ^ rx7) * 8;
    int qa1 = ((4 + quad) ^ rx7) * 8;

    for (int kc = 0; kc < 256; kc += 64) {
#pragma unroll
        for (int j = 0; j < 4; j++) {
            GLOAD_LDS16(gA + kc + j * 32 * 256, lA + j * 2048);
            GLOAD_LDS16(gB + kc + j * 32 * 256, lB + j * 2048);
        }
        __syncthreads();
        bf16x8 a[4][2], b[4][2];
#pragma unroll
        for (int i = 0; i < 4; i++) {
            a[i][0] = *(const bf16x8*)(pw + i * 16 * 64 + qa0);  // We
            a[i][1] = *(const bf16x8*)(pw + i * 16 * 64 + qa1);
            b[i][0] = *(const bf16x8*)(pq + i * 16 * 64 + qa0);  // Q
            b[i][1] = *(const bf16x8*)(pq + i * 16 * 64 + qa1);
        }
#pragma unroll
        for (int kh = 0; kh < 2; kh++)
#pragma unroll
            for (int i = 0; i < 4; i++)
#pragma unroll
                for (int j = 0; j < 4; j++)
                    acc[i][j] = __builtin_amdgcn_mfma_f32_16x16x32_bf16(
                        a[i][kh], b[j][kh], acc[i][j], 0, 0, 0);
        __syncthreads();
    }

    // ---- epilogue: silu -> bf16 pack (registers) -> MFMA reduction ----
    // acc[i][j] element r: We-row n = wA*64+i*16+quad*4+r ; Q-row m = wB*64+j*16+lcol
    u32 ps[4][4][2];
#pragma unroll
    for (int i = 0; i < 4; i++)
#pragma unroll
        for (int j = 0; j < 4; j++) {
            ps[i][j][0] = pk2(silu(acc[i][j][0]), silu(acc[i][j][1]));
            ps[i][j][1] = pk2(silu(acc[i][j][2]), silu(acc[i][j][3]));
        }

    int srcbase = (quad & 1) * 32 + lcol;  // lane id of b=0 source quad
    bool hi = quad >= 2;
    f32x4 zero = {};
#pragma unroll
    for (int g = 0; g < 2; g++) {
        int gg = (n0 + wA * 64 + g * 32) >> 5;
        bf16x8 afrag = *(const bf16x8*)(Rb + ((size_t)(gg * 16 + lcol) * 32 + quad * 8));
        float sb0 = SB[gg * 2 + 0], sb1 = SB[gg * 2 + 1], ab = AB[gg];
#pragma unroll
        for (int j = 0; j < 4; j++) {
            union { u32 u[4]; bf16x8 v; } bf;
#pragma unroll
            for (int b = 0; b < 2; b++) {
                int s = srcbase + b * 16;
#pragma unroll
                for (int c = 0; c < 2; c++) {
                    u32 x0 = (u32)__shfl((int)ps[2 * g + 0][j][c], s);
                    u32 x1 = (u32)__shfl((int)ps[2 * g + 1][j][c], s);
                    bf.u[b * 2 + c] = hi ? x1 : x0;
                }
            }
            f32x4 d2 = __builtin_amdgcn_mfma_f32_16x16x32_bf16(afrag, bf.v, zero, 0, 0, 0);
            if (quad == 0) {   // rows j_out = 0..3 live in quad 0; use 0..2
                int m = m0 + wB * 64 + j * 16 + lcol;
                size_t oi = ((size_t)m * NGRP + gg) * 2;
                offs_out[oi + 0] = d2[0] + sb0;
                offs_out[oi + 1] = d2[1] + sb1;
                aw_out[(size_t)m * NGRP + gg] = d2[2] + ab;
            }
        }
    }
}

// ---------------- stage A: value projection (bf16 MFMA) -> Vt bf16 transposed ----------------
__global__ __launch_bounds__(256) void k_value_mfma(
    const unsigned short* __restrict__ Xb,   // (21760,256) bf16
    const unsigned short* __restrict__ Wvb,  // (256,256) bf16 (n,k)
    const float* __restrict__ bias,          // (256)
    unsigned short* __restrict__ Vtb)        // (4,8,5440,32) bf16
{
    __shared__ short sA[128 * 64];
    __shared__ short sB[128 * 64];
    int tid = threadIdx.x;
    int n0 = blockIdx.x * 128;
    int m0 = blockIdx.y * 128;
    int lane = tid & 63;
    int w = tid >> 6;
    int wm = w >> 1, wn = w & 1;
    int lcol = lane & 15, lrow = lane >> 4;

    int srow = tid >> 3;
    int sq = (tid & 7) ^ (srow & 7);
    const short* gA = (const short*)Xb + (size_t)(m0 + srow) * 256 + sq * 8;
    const short* gB = (const short*)Wvb + (size_t)(n0 + srow) * 256 + sq * 8;
    short* lA = sA + w * 512;
    short* lB = sB + w * 512;

    f32x4 acc[4][4] = {};
    const short* pa = sA + (wm * 64 + lcol) * 64;
    const short* pb = sB + (wn * 64 + lcol) * 64;
    int rx7 = lcol & 7;
    int qa0 = (lrow ^ rx7) * 8;
    int qa1 = ((4 + lrow) ^ rx7) * 8;

    for (int kc = 0; kc < 256; kc += 64) {
#pragma unroll
        for (int j = 0; j < 4; j++) {
            GLOAD_LDS16(gA + kc + j * 32 * 256, lA + j * 2048);
            GLOAD_LDS16(gB + kc + j * 32 * 256, lB + j * 2048);
        }
        __syncthreads();
        bf16x8 a[4][2], b[4][2];
#pragma unroll
        for (int i = 0; i < 4; i++) {
            a[i][0] = *(const bf16x8*)(pa + i * 16 * 64 + qa0);
            a[i][1] = *(const bf16x8*)(pa + i * 16 * 64 + qa1);
            b[i][0] = *(const bf16x8*)(pb + i * 16 * 64 + qa0);
            b[i][1] = *(const bf16x8*)(pb + i * 16 * 64 + qa1);
        }
#pragma unroll
        for (int kh = 0; kh < 2; kh++)
#pragma unroll
            for (int mi = 0; mi < 4; mi++)
#pragma unroll
                for (int ni = 0; ni < 4; ni++)
                    acc[mi][ni] = __builtin_amdgcn_mfma_f32_16x16x32_bf16(
                        a[mi][kh], b[ni][kh], acc[mi][ni], 0, 0, 0);
        __syncthreads();
    }

#pragma unroll
    for (int mi = 0; mi < 4; mi++) {
#pragma unroll
        for (int ni = 0; ni < 4; ni++) {
            int n = n0 + wn * 64 + ni * 16 + lcol;
            int h = n >> 5, d = n & 31;
            float bn = bias[n];
#pragma unroll
            for (int r = 0; r < 4; r++) {
                int m = m0 + wm * 64 + mi * 16 + lrow * 4 + r;
                int b = m / LQ, q = m - b * LQ;
                Vtb[(((size_t)b * NH + h) * LQ + q) * DH + d] = f2bf(acc[mi][ni][r] + bn);
            }
        }
    }
}

// ---------------- stage D: output projection (bf16 MFMA) ----------------
__global__ __launch_bounds__(256) void k_out_mfma(
    const unsigned short* __restrict__ Xb,   // (21760,256) bf16 attn
    const unsigned short* __restrict__ Wob,  // (256,256) bf16 (n,k)
    const float* __restrict__ bias,          // (256)
    float* __restrict__ Out)                 // (21760,256) fp32
{
    __shared__ short sA[128 * 64];
    __shared__ short sB[128 * 64];
    int tid = threadIdx.x;
    int n0 = blockIdx.x * 128;
    int m0 = blockIdx.y * 128;
    int lane = tid & 63;
    int w = tid >> 6;
    int wm = w >> 1, wn = w & 1;
    int lcol = lane & 15, lrow = lane >> 4;

    int srow = tid >> 3;
    int sq = (tid & 7) ^ (srow & 7);
    const short* gA = (const short*)Xb + (size_t)(m0 + srow) * 256 + sq * 8;
    const short* gB = (const short*)Wob + (size_t)(n0 + srow) * 256 + sq * 8;
    short* lA = sA + w * 512;
    short* lB = sB + w * 512;

    f32x4 acc[4][4] = {};
    const short* pa = sA + (wm * 64 + lcol) * 64;
    const short* pb = sB + (wn * 64 + lcol) * 64;
    int rx7 = lcol & 7;
    int qa0 = (lrow ^ rx7) * 8;
    int qa1 = ((4 + lrow) ^ rx7) * 8;

    for (int kc = 0; kc < 256; kc += 64) {
#pragma unroll
        for (int j = 0; j < 4; j++) {
            GLOAD_LDS16(gA + kc + j * 32 * 256, lA + j * 2048);
            GLOAD_LDS16(gB + kc + j * 32 * 256, lB + j * 2048);
        }
        __syncthreads();
        bf16x8 a[4][2], b[4][2];
#pragma unroll
        for (int i = 0; i < 4; i++) {
            a[i][0] = *(const bf16x8*)(pa + i * 16 * 64 + qa0);
            a[i][1] = *(const bf16x8*)(pa + i * 16 * 64 + qa1);
            b[i][0] = *(const bf16x8*)(pb + i * 16 * 64 + qa0);
            b[i][1] = *(const bf16x8*)(pb + i * 16 * 64 + qa1);
        }
#pragma unroll
        for (int kh = 0; kh < 2; kh++)
#pragma unroll
            for (int mi = 0; mi < 4; mi++)
#pragma unroll
                for (int ni = 0; ni < 4; ni++)
                    acc[mi][ni] = __builtin_amdgcn_mfma_f32_16x16x32_bf16(
                        a[mi][kh], b[ni][kh], acc[mi][ni], 0, 0, 0);
        __syncthreads();
    }

#pragma unroll
    for (int mi = 0; mi < 4; mi++) {
#pragma unroll
        for (int ni = 0; ni < 4; ni++) {
            int n = n0 + wn * 64 + ni * 16 + lcol;
            float bn = bias[n];
#pragma unroll
            for (int r = 0; r < 4; r++) {
                int m = m0 + wm * 64 + mi * 16 + lrow * 4 + r;
                Out[(size_t)m * 256 + n] = acc[mi][ni][r] + bn;
            }
        }
    }
}

// ---------------- stage C: softmax + bilinear sampling (prep-in-LDS) ----------------
__global__ __launch_bounds__(256) void k_sample(
    const unsigned short* __restrict__ Vtb,  // (4,8,5440,32) bf16
    const float* __restrict__ refp,          // (4,5440,4,2)
    const float* __restrict__ offs,          // (M,128,2)
    const float* __restrict__ awl,           // (M,128)
    unsigned short* __restrict__ atnb)       // (M,256) bf16
{
    int m = blockIdx.x;
    int tid = threadIdx.x;
    __shared__ int   s_idx[128][4];
    __shared__ float s_w[128][4];

    if (tid < 128) {
        int p = tid;
        int l = (p >> 2) & 3;
        float logit = awl[(size_t)m * 128 + p];
        float mx = logit;
#pragma unroll
        for (int off = 1; off < 16; off <<= 1) mx = fmaxf(mx, __shfl_xor(mx, off));
        float e = __expf(logit - mx);
        float s = e;
#pragma unroll
        for (int off = 1; off < 16; off <<= 1) s += __shfl_xor(s, off);
        float prob = e / s;

        float ox = offs[((size_t)m * 128 + p) * 2 + 0];
        float oy = offs[((size_t)m * 128 + p) * 2 + 1];
        float rx = refp[(size_t)m * 8 + l * 2 + 0];
        float ry = refp[(size_t)m * 8 + l * 2 + 1];
        int Wl = 64 >> l;
        int base = (l == 0) ? 0 : (l == 1) ? 4096 : (l == 2) ? 5120 : 5376;
        float fW = (float)Wl;
        float x = rx * fW + ox - 0.5f;
        float y = ry * fW + oy - 0.5f;
        float x0f = floorf(x), y0f = floorf(y);
        float wx = x - x0f, wy = y - y0f;
        int x0 = (int)x0f, y0 = (int)y0f;
        int xc0 = min(max(x0, 0), Wl - 1), xc1 = min(max(x0 + 1, 0), Wl - 1);
        int yc0 = min(max(y0, 0), Wl - 1), yc1 = min(max(y0 + 1, 0), Wl - 1);
        float vx0 = (x0 >= 0 && x0 < Wl) ? 1.f : 0.f;
        float vx1 = (x0 + 1 >= 0 && x0 + 1 < Wl) ? 1.f : 0.f;
        float vy0 = (y0 >= 0 && y0 < Wl) ? 1.f : 0.f;
        float vy1 = (y0 + 1 >= 0 && y0 + 1 < Wl) ? 1.f : 0.f;
        s_idx[p][0] = (base + yc0 * Wl + xc0) * DH;
        s_idx[p][1] = (base + yc0 * Wl + xc1) * DH;
        s_idx[p][2] = (base + yc1 * Wl + xc0) * DH;
        s_idx[p][3] = (base + yc1 * Wl + xc1) * DH;
        s_w[p][0] = prob * (1.f - wx) * (1.f - wy) * vx0 * vy0;
        s_w[p][1] = prob * wx * (1.f - wy) * vx1 * vy0;
        s_w[p][2] = prob * (1.f - wx) * wy * vx0 * vy1;
        s_w[p][3] = prob * wx * wy * vx1 * vy1;
    }
    __syncthreads();

    int h = tid >> 5, d = tid & 31;
    int b = m / LQ;
    const unsigned short* vb = Vtb + ((size_t)b * NH + h) * LQ * DH + d;
    float acc = 0.f;
#pragma unroll
    for (int p16 = 0; p16 < 16; p16++) {
        int p = h * 16 + p16;
        int4 ri = *(const int4*)s_idx[p];
        float4 wv = *(const float4*)s_w[p];
        float v00 = bf2f(vb[ri.x]);
        float v01 = bf2f(vb[ri.y]);
        float v10 = bf2f(vb[ri.z]);
        float v11 = bf2f(vb[ri.w]);
        acc += wv.x * v00 + wv.y * v01 + wv.z * v10 + wv.w * v11;
    }
    atnb[(size_t)m * 256 + tid] = f2bf(acc);
}

// ---------------- launch ----------------
extern "C" void kernel_launch(void* const* d_in, const int* in_sizes, int n_in,
                              void* d_out, int out_size, void* d_ws, size_t ws_size,
                              hipStream_t stream) {
    const float* query  = (const float*)d_in[0];
    const float* refp   = (const float*)d_in[1];
    const float* inflat = (const float*)d_in[2];
    // d_in[3] = input_spatial_shapes (static, unused)
    const float* We  = (const float*)d_in[4];
    const float* SW  = (const float*)d_in[5];
    const float* SB  = (const float*)d_in[6];
    const float* AWw = (const float*)d_in[7];
    const float* ABb = (const float*)d_in[8];
    const float* VW  = (const float*)d_in[9];
    const float* Vb  = (const float*)d_in[10];
    const float* OW  = (const float*)d_in[11];
    const float* Ob  = (const float*)d_in[12];
    float* out = (float*)d_out;

    float* ws = (float*)d_ws;
    unsigned short* Vtb  = (unsigned short*)ws;                    // 5,570,560 shorts
    float* offs          = ws + 2785280;                           // 5,570,560 f
    float* awl           = offs + 5570560;                         // 2,785,280 f
    unsigned short* Qbf  = (unsigned short*)(awl + 2785280);       // 5,570,560 shorts
    unsigned short* Webf = Qbf + 5570560;                          // 1,048,576 shorts
    unsigned short* Xbf  = Webf + 1048576;                         // 5,570,560 shorts
    unsigned short* Wvbf = Xbf + 5570560;                          // 65,536 shorts
    unsigned short* OWbf = Wvbf + 65536;                           // 65,536 shorts
    unsigned short* Rbf  = OWbf + 65536;                           // 65,536 shorts
    unsigned short* atnb = Xbf;   // alias: Xbf consumed by k_value_mfma before k_sample writes

    k_cvt2<<<dim3(5440, 2), 256, 0, stream>>>(query, Qbf, inflat, Xbf, MTOT * 256 / 4);
    k_cvt3<<<dim3(1024, 3), 256, 0, stream>>>(We, Webf, OEN * 256 / 4,
                                              VW, Wvbf, 256 * 256 / 4,
                                              OW, OWbf, 256 * 256 / 4);
    k_prep_r<<<dim3(256), 256, 0, stream>>>(SW, AWw, Rbf);

    k_value_mfma<<<dim3(2, MTOT / 128), 256, 0, stream>>>(Xbf, Wvbf, Vb, Vtb);

    k_oe_mfma<<<dim3(OEN / 128, MTOT / 128), 256, 0, stream>>>(
        Qbf, Webf, Rbf, SB, ABb, offs, awl);

    k_sample<<<dim3(MTOT), 256, 0, stream>>>(Vtb, refp, offs, awl, atnb);

    k_out_mfma<<<dim3(2, MTOT / 128), 256, 0, stream>>>(atnb, OWbf, Ob, out);
}

// Round 5
// 260.658 us; speedup vs baseline: 3.4425x; 1.1069x over previous
//
#include <hip/hip_runtime.h>
#include <hip/hip_bf16.h>

// ---------------- problem constants (static pyramid) ----------------
#define NB 4
#define LQ 5440
#define DM 256
#define NH 8
#define NL 4
#define NP 4
#define OFFD 32
#define DH 32
#define MTOT (NB * LQ)             // 21760
#define OEN (NH * NL * NP * OFFD)  // 4096
#define NGRP (NH * NL * NP)        // 128

typedef __attribute__((ext_vector_type(8))) short bf16x8;
typedef __attribute__((ext_vector_type(4))) float f32x4;
typedef unsigned int u32;

#define GLOAD_LDS16(gp, lp) \
    __builtin_amdgcn_global_load_lds((const __attribute__((address_space(1))) u32*)(gp), \
                                     (__attribute__((address_space(3))) u32*)(lp), 16, 0, 0)

__device__ __forceinline__ float bf2f(unsigned short u) {
    union { unsigned int i; float f; } v; v.i = ((unsigned int)u) << 16; return v.f;
}
// cheap RNE f32->bf16 (no NaN path; all values finite here). Matches RNE rounding.
__device__ __forceinline__ unsigned short f2bf(float x) {
    u32 u = __float_as_uint(x);
    u = u + 0x7fffu + ((u >> 16) & 1u);
    return (unsigned short)(u >> 16);
}
__device__ __forceinline__ u32 pk2(float a, float b) {
    u32 ua = __float_as_uint(a), ub = __float_as_uint(b);
    ua = ua + 0x7fffu + ((ua >> 16) & 1u);
    ub = ub + 0x7fffu + ((ub >> 16) & 1u);
    return (ua >> 16) | (ub & 0xffff0000u);
}
__device__ __forceinline__ float silu(float x) {
    float e = __expf(-x);
    return x * __builtin_amdgcn_rcpf(1.0f + e);   // v_rcp_f32, ~1 ulp
}

// ---------------- fp32 -> bf16 conversions ----------------
__global__ __launch_bounds__(256) void k_cvt2(
    const float* __restrict__ A, unsigned short* __restrict__ Ao,
    const float* __restrict__ B, unsigned short* __restrict__ Bo, int n4)
{
    int i = blockIdx.x * 256 + threadIdx.x;
    if (i >= n4) return;
    const float* src = blockIdx.y ? B : A;
    unsigned short* dst = blockIdx.y ? Bo : Ao;
    float4 v = *(const float4*)(src + (size_t)i * 4);
    ushort4 o;
    o.x = f2bf(v.x); o.y = f2bf(v.y); o.z = f2bf(v.z); o.w = f2bf(v.w);
    *(ushort4*)(dst + (size_t)i * 4) = o;
}
__global__ __launch_bounds__(256) void k_cvt3(
    const float* __restrict__ A, unsigned short* __restrict__ Ao, int nA4,
    const float* __restrict__ B, unsigned short* __restrict__ Bo, int nB4,
    const float* __restrict__ C, unsigned short* __restrict__ Co, int nC4)
{
    int i = blockIdx.x * 256 + threadIdx.x;
    const float* src; unsigned short* dst; int n4;
    if (blockIdx.y == 0)      { src = A; dst = Ao; n4 = nA4; }
    else if (blockIdx.y == 1) { src = B; dst = Bo; n4 = nB4; }
    else                      { src = C; dst = Co; n4 = nC4; }
    if (i >= n4) return;
    float4 v = *(const float4*)(src + (size_t)i * 4);
    ushort4 o;
    o.x = f2bf(v.x); o.y = f2bf(v.y); o.z = f2bf(v.z); o.w = f2bf(v.w);
    *(ushort4*)(dst + (size_t)i * 4) = o;
}

// ---------------- prepack reduction weights: Rb[gg][j16][d32] bf16 ----------------
__global__ __launch_bounds__(256) void k_prep_r(
    const float* __restrict__ SW, const float* __restrict__ AW,
    unsigned short* __restrict__ Rb)
{
    int idx = blockIdx.x * 256 + threadIdx.x;   // 65536 total
    int gg = idx >> 9, jo = (idx >> 5) & 15, d = idx & 31;
    float v = 0.f;
    if (jo == 0)      v = SW[(gg * 32 + d) * 2 + 0];
    else if (jo == 1) v = SW[(gg * 32 + d) * 2 + 1];
    else if (jo == 2) v = AW[gg * 32 + d];
    Rb[idx] = f2bf(v);
}

// ============================================================================
// Stage B: MFMA bf16 GEMM (A=We, B=Q -> acc n-major) + silu + MFMA reduction.
// ============================================================================
__global__ __launch_bounds__(256) void k_oe_mfma(
    const unsigned short* __restrict__ Qb,   // (21760,256) bf16
    const unsigned short* __restrict__ Wb,   // (4096,256) bf16
    const unsigned short* __restrict__ Rb,   // (128,16,32) bf16 reduction frags
    const float* __restrict__ SB,    // (128,2)
    const float* __restrict__ AB,    // (128)
    float* __restrict__ offs_out,    // (M,128,2)
    float* __restrict__ aw_out)      // (M,128)
{
    __shared__ short sA[128 * 64];   // Q rows
    __shared__ short sB[128 * 64];   // We rows
    int tid = threadIdx.x;
    int n0 = blockIdx.x * 128;   // We/n fastest-varying -> blocks share Q via L2
    int m0 = blockIdx.y * 128;

    int lane = tid & 63;
    int w = tid >> 6;
    int wA = w >> 1;            // We half (mfma-m)
    int wB = w & 1;             // Q half (mfma-n)
    int lcol = lane & 15, quad = lane >> 4;

    int srow = tid >> 3;
    int sq = (tid & 7) ^ (srow & 7);
    const short* gA = (const short*)Qb + (size_t)(m0 + srow) * 256 + sq * 8;
    const short* gB = (const short*)Wb + (size_t)(n0 + srow) * 256 + sq * 8;
    short* lA = sA + w * 512;
    short* lB = sB + w * 512;

    f32x4 acc[4][4] = {};   // [We-tile i][Q-tile j]

    const short* pq = sA + (wB * 64 + lcol) * 64;   // Q fragments (B operand)
    const short* pw = sB + (wA * 64 + lcol) * 64;   // We fragments (A operand)
    int rx7 = lcol & 7;
    int qa0 = (quad ^ rx7) * 8;
    int qa1 = ((4 + quad) ^ rx7) * 8;

    for (int kc = 0; kc < 256; kc += 64) {
#pragma unroll
        for (int j = 0; j < 4; j++) {
            GLOAD_LDS16(gA + kc + j * 32 * 256, lA + j * 2048);
            GLOAD_LDS16(gB + kc + j * 32 * 256, lB + j * 2048);
        }
        __syncthreads();
        bf16x8 a[4][2], b[4][2];
#pragma unroll
        for (int i = 0; i < 4; i++) {
            a[i][0] = *(const bf16x8*)(pw + i * 16 * 64 + qa0);  // We
            a[i][1] = *(const bf16x8*)(pw + i * 16 * 64 + qa1);
            b[i][0] = *(const bf16x8*)(pq + i * 16 * 64 + qa0);  // Q
            b[i][1] = *(const bf16x8*)(pq + i * 16 * 64 + qa1);
        }
#pragma unroll
        for (int kh = 0; kh < 2; kh++)
#pragma unroll
            for (int i = 0; i < 4; i++)
#pragma unroll
                for (int j = 0; j < 4; j++)
                    acc[i][j] = __builtin_amdgcn_mfma_f32_16x16x32_bf16(
                        a[i][kh], b[j][kh], acc[i][j], 0, 0, 0);
        __syncthreads();
    }

    // ---- epilogue: silu -> bf16 pack (registers) -> MFMA reduction ----
    u32 ps[4][4][2];
#pragma unroll
    for (int i = 0; i < 4; i++)
#pragma unroll
        for (int j = 0; j < 4; j++) {
            ps[i][j][0] = pk2(silu(acc[i][j][0]), silu(acc[i][j][1]));
            ps[i][j][1] = pk2(silu(acc[i][j][2]), silu(acc[i][j][3]));
        }

    int srcbase = (quad & 1) * 32 + lcol;
    bool hi = quad >= 2;
    f32x4 zero = {};
#pragma unroll
    for (int g = 0; g < 2; g++) {
        int gg = (n0 + wA * 64 + g * 32) >> 5;
        bf16x8 afrag = *(const bf16x8*)(Rb + ((size_t)(gg * 16 + lcol) * 32 + quad * 8));
        float sb0 = SB[gg * 2 + 0], sb1 = SB[gg * 2 + 1], ab = AB[gg];
#pragma unroll
        for (int j = 0; j < 4; j++) {
            union { u32 u[4]; bf16x8 v; } bf;
#pragma unroll
            for (int b = 0; b < 2; b++) {
                int s = srcbase + b * 16;
#pragma unroll
                for (int c = 0; c < 2; c++) {
                    u32 x0 = (u32)__shfl((int)ps[2 * g + 0][j][c], s);
                    u32 x1 = (u32)__shfl((int)ps[2 * g + 1][j][c], s);
                    bf.u[b * 2 + c] = hi ? x1 : x0;
                }
            }
            f32x4 d2 = __builtin_amdgcn_mfma_f32_16x16x32_bf16(afrag, bf.v, zero, 0, 0, 0);
            if (quad == 0) {
                int m = m0 + wB * 64 + j * 16 + lcol;
                size_t oi = ((size_t)m * NGRP + gg) * 2;
                offs_out[oi + 0] = d2[0] + sb0;
                offs_out[oi + 1] = d2[1] + sb1;
                aw_out[(size_t)m * NGRP + gg] = d2[2] + ab;
            }
        }
    }
}

// ---------------- stage A: value projection (bf16 MFMA) -> Vt bf16 transposed ----------------
__global__ __launch_bounds__(256) void k_value_mfma(
    const unsigned short* __restrict__ Xb,   // (21760,256) bf16
    const unsigned short* __restrict__ Wvb,  // (256,256) bf16 (n,k)
    const float* __restrict__ bias,          // (256)
    unsigned short* __restrict__ Vtb)        // (4,8,5440,32) bf16
{
    __shared__ short sA[128 * 64];
    __shared__ short sB[128 * 64];
    int tid = threadIdx.x;
    int n0 = blockIdx.x * 128;
    int m0 = blockIdx.y * 128;
    int lane = tid & 63;
    int w = tid >> 6;
    int wm = w >> 1, wn = w & 1;
    int lcol = lane & 15, lrow = lane >> 4;

    int srow = tid >> 3;
    int sq = (tid & 7) ^ (srow & 7);
    const short* gA = (const short*)Xb + (size_t)(m0 + srow) * 256 + sq * 8;
    const short* gB = (const short*)Wvb + (size_t)(n0 + srow) * 256 + sq * 8;
    short* lA = sA + w * 512;
    short* lB = sB + w * 512;

    f32x4 acc[4][4] = {};
    const short* pa = sA + (wm * 64 + lcol) * 64;
    const short* pb = sB + (wn * 64 + lcol) * 64;
    int rx7 = lcol & 7;
    int qa0 = (lrow ^ rx7) * 8;
    int qa1 = ((4 + lrow) ^ rx7) * 8;

    for (int kc = 0; kc < 256; kc += 64) {
#pragma unroll
        for (int j = 0; j < 4; j++) {
            GLOAD_LDS16(gA + kc + j * 32 * 256, lA + j * 2048);
            GLOAD_LDS16(gB + kc + j * 32 * 256, lB + j * 2048);
        }
        __syncthreads();
        bf16x8 a[4][2], b[4][2];
#pragma unroll
        for (int i = 0; i < 4; i++) {
            a[i][0] = *(const bf16x8*)(pa + i * 16 * 64 + qa0);
            a[i][1] = *(const bf16x8*)(pa + i * 16 * 64 + qa1);
            b[i][0] = *(const bf16x8*)(pb + i * 16 * 64 + qa0);
            b[i][1] = *(const bf16x8*)(pb + i * 16 * 64 + qa1);
        }
#pragma unroll
        for (int kh = 0; kh < 2; kh++)
#pragma unroll
            for (int mi = 0; mi < 4; mi++)
#pragma unroll
                for (int ni = 0; ni < 4; ni++)
                    acc[mi][ni] = __builtin_amdgcn_mfma_f32_16x16x32_bf16(
                        a[mi][kh], b[ni][kh], acc[mi][ni], 0, 0, 0);
        __syncthreads();
    }

#pragma unroll
    for (int mi = 0; mi < 4; mi++) {
#pragma unroll
        for (int ni = 0; ni < 4; ni++) {
            int n = n0 + wn * 64 + ni * 16 + lcol;
            int h = n >> 5, d = n & 31;
            float bn = bias[n];
#pragma unroll
            for (int r = 0; r < 4; r++) {
                int m = m0 + wm * 64 + mi * 16 + lrow * 4 + r;
                int b = m / LQ, q = m - b * LQ;
                Vtb[(((size_t)b * NH + h) * LQ + q) * DH + d] = f2bf(acc[mi][ni][r] + bn);
            }
        }
    }
}

// ---------------- stage D: output projection (bf16 MFMA) ----------------
__global__ __launch_bounds__(256) void k_out_mfma(
    const unsigned short* __restrict__ Xb,   // (21760,256) bf16 attn
    const unsigned short* __restrict__ Wob,  // (256,256) bf16 (n,k)
    const float* __restrict__ bias,          // (256)
    float* __restrict__ Out)                 // (21760,256) fp32
{
    __shared__ short sA[128 * 64];
    __shared__ short sB[128 * 64];
    int tid = threadIdx.x;
    int n0 = blockIdx.x * 128;
    int m0 = blockIdx.y * 128;
    int lane = tid & 63;
    int w = tid >> 6;
    int wm = w >> 1, wn = w & 1;
    int lcol = lane & 15, lrow = lane >> 4;

    int srow = tid >> 3;
    int sq = (tid & 7) ^ (srow & 7);
    const short* gA = (const short*)Xb + (size_t)(m0 + srow) * 256 + sq * 8;
    const short* gB = (const short*)Wob + (size_t)(n0 + srow) * 256 + sq * 8;
    short* lA = sA + w * 512;
    short* lB = sB + w * 512;

    f32x4 acc[4][4] = {};
    const short* pa = sA + (wm * 64 + lcol) * 64;
    const short* pb = sB + (wn * 64 + lcol) * 64;
    int rx7 = lcol & 7;
    int qa0 = (lrow ^ rx7) * 8;
    int qa1 = ((4 + lrow) ^ rx7) * 8;

    for (int kc = 0; kc < 256; kc += 64) {
#pragma unroll
        for (int j = 0; j < 4; j++) {
            GLOAD_LDS16(gA + kc + j * 32 * 256, lA + j * 2048);
            GLOAD_LDS16(gB + kc + j * 32 * 256, lB + j * 2048);
        }
        __syncthreads();
        bf16x8 a[4][2], b[4][2];
#pragma unroll
        for (int i = 0; i < 4; i++) {
            a[i][0] = *(const bf16x8*)(pa + i * 16 * 64 + qa0);
            a[i][1] = *(const bf16x8*)(pa + i * 16 * 64 + qa1);
            b[i][0] = *(const bf16x8*)(pb + i * 16 * 64 + qa0);
            b[i][1] = *(const bf16x8*)(pb + i * 16 * 64 + qa1);
        }
#pragma unroll
        for (int kh = 0; kh < 2; kh++)
#pragma unroll
            for (int mi = 0; mi < 4; mi++)
#pragma unroll
                for (int ni = 0; ni < 4; ni++)
                    acc[mi][ni] = __builtin_amdgcn_mfma_f32_16x16x32_bf16(
                        a[mi][kh], b[ni][kh], acc[mi][ni], 0, 0, 0);
        __syncthreads();
    }

#pragma unroll
    for (int mi = 0; mi < 4; mi++) {
#pragma unroll
        for (int ni = 0; ni < 4; ni++) {
            int n = n0 + wn * 64 + ni * 16 + lcol;
            float bn = bias[n];
#pragma unroll
            for (int r = 0; r < 4; r++) {
                int m = m0 + wm * 64 + mi * 16 + lrow * 4 + r;
                Out[(size_t)m * 256 + n] = acc[mi][ni][r] + bn;
            }
        }
    }
}

// ---------------- stage C: softmax + bilinear sampling ----------------
// Block = 256 thr = 4 waves, handles 4 consecutive m. Wave wv owns m_base+wv.
// Lane = (corner=lane>>4, dword i=lane&15): ONE global_load_dword fetches all
// 4 corner rows (4 x 64 B) of a point. Corner-reduce via 2 shfl_xor.
__global__ __launch_bounds__(256) void k_sample(
    const unsigned short* __restrict__ Vtb,  // (4,8,5440,32) bf16
    const float* __restrict__ refp,          // (4,5440,4,2)
    const float* __restrict__ offs,          // (M,128,2)
    const float* __restrict__ awl,           // (M,128)
    unsigned short* __restrict__ atnb)       // (M,256) bf16
{
    int tid = threadIdx.x;
    int m_base = blockIdx.x * 4;
    __shared__ int2 s_iw[4][128][4];   // {byte offset, weight bits}

    // ---- prep: 512 (mloc,point) pairs on 256 threads, 2 reps ----
#pragma unroll
    for (int rep = 0; rep < 2; rep++) {
        int p = tid & 127;
        int mloc = (tid >> 7) + rep * 2;
        int m = m_base + mloc;
        int l = (p >> 2) & 3;
        float logit = awl[(size_t)m * 128 + p];
        float mx = logit;
#pragma unroll
        for (int off = 1; off < 16; off <<= 1) mx = fmaxf(mx, __shfl_xor(mx, off));
        float e = __expf(logit - mx);
        float s = e;
#pragma unroll
        for (int off = 1; off < 16; off <<= 1) s += __shfl_xor(s, off);
        float prob = e * __builtin_amdgcn_rcpf(s);

        float ox = offs[((size_t)m * 128 + p) * 2 + 0];
        float oy = offs[((size_t)m * 128 + p) * 2 + 1];
        float rx = refp[(size_t)m * 8 + l * 2 + 0];
        float ry = refp[(size_t)m * 8 + l * 2 + 1];
        int Wl = 64 >> l;
        int base = (l == 0) ? 0 : (l == 1) ? 4096 : (l == 2) ? 5120 : 5376;
        float fW = (float)Wl;
        float x = rx * fW + ox - 0.5f;
        float y = ry * fW + oy - 0.5f;
        float x0f = floorf(x), y0f = floorf(y);
        float wx = x - x0f, wy = y - y0f;
        int x0 = (int)x0f, y0 = (int)y0f;
        int xc0 = min(max(x0, 0), Wl - 1), xc1 = min(max(x0 + 1, 0), Wl - 1);
        int yc0 = min(max(y0, 0), Wl - 1), yc1 = min(max(y0 + 1, 0), Wl - 1);
        float vx0 = (x0 >= 0 && x0 < Wl) ? 1.f : 0.f;
        float vx1 = (x0 + 1 < Wl) ? 1.f : 0.f;          // x0+1 >= 0 always if vx0 or x0=-1
        float vy0 = (y0 >= 0 && y0 < Wl) ? 1.f : 0.f;
        float vy1 = (y0 + 1 < Wl) ? 1.f : 0.f;
        if (x0 + 1 < 0) vx1 = 0.f;
        if (y0 + 1 < 0) vy1 = 0.f;
        // byte offsets into a head's value plane (row = 32 bf16 = 64 B)
        s_iw[mloc][p][0] = make_int2((base + yc0 * Wl + xc0) * 64,
                                     __float_as_int(prob * (1.f - wx) * (1.f - wy) * vx0 * vy0));
        s_iw[mloc][p][1] = make_int2((base + yc0 * Wl + xc1) * 64,
                                     __float_as_int(prob * wx * (1.f - wy) * vx1 * vy0));
        s_iw[mloc][p][2] = make_int2((base + yc1 * Wl + xc0) * 64,
                                     __float_as_int(prob * (1.f - wx) * wy * vx0 * vy1));
        s_iw[mloc][p][3] = make_int2((base + yc1 * Wl + xc1) * 64,
                                     __float_as_int(prob * wx * wy * vx1 * vy1));
    }
    __syncthreads();

    // ---- gather: wave wv = query m_base+wv; lane = (corner, dword) ----
    int wv = tid >> 6, lane = tid & 63;
    int corner = lane >> 4, il = lane & 15;
    int m = m_base + wv;
    int b = m / LQ;
    const char* vB = (const char*)(Vtb + (size_t)b * NH * LQ * DH);
#pragma unroll
    for (int h = 0; h < 8; h++) {
        const char* ph = vB + (size_t)h * LQ * DH * 2 + il * 4;
        float a0 = 0.f, a1 = 0.f;
#pragma unroll
        for (int p16 = 0; p16 < 16; p16++) {
            int2 iw = s_iw[wv][h * 16 + p16][corner];
            u32 v = *(const u32*)(ph + iw.x);
            float wgt = __int_as_float(iw.y);
            a0 += wgt * __uint_as_float(v << 16);            // lo bf16
            a1 += wgt * __uint_as_float(v & 0xffff0000u);    // hi bf16
        }
        a0 += __shfl_xor(a0, 16); a0 += __shfl_xor(a0, 32);
        a1 += __shfl_xor(a1, 16); a1 += __shfl_xor(a1, 32);
        if (corner == 0) {
            ((u32*)atnb)[(size_t)m * 128 + h * 16 + il] = pk2(a0, a1);
        }
    }
}

// ---------------- launch ----------------
extern "C" void kernel_launch(void* const* d_in, const int* in_sizes, int n_in,
                              void* d_out, int out_size, void* d_ws, size_t ws_size,
                              hipStream_t stream) {
    const float* query  = (const float*)d_in[0];
    const float* refp   = (const float*)d_in[1];
    const float* inflat = (const float*)d_in[2];
    // d_in[3] = input_spatial_shapes (static, unused)
    const float* We  = (const float*)d_in[4];
    const float* SW  = (const float*)d_in[5];
    const float* SB  = (const float*)d_in[6];
    const float* AWw = (const float*)d_in[7];
    const float* ABb = (const float*)d_in[8];
    const float* VW  = (const float*)d_in[9];
    const float* Vb  = (const float*)d_in[10];
    const float* OW  = (const float*)d_in[11];
    const float* Ob  = (const float*)d_in[12];
    float* out = (float*)d_out;

    float* ws = (float*)d_ws;
    unsigned short* Vtb  = (unsigned short*)ws;                    // 5,570,560 shorts
    float* offs          = ws + 2785280;                           // 5,570,560 f
    float* awl           = offs + 5570560;                         // 2,785,280 f
    unsigned short* Qbf  = (unsigned short*)(awl + 2785280);       // 5,570,560 shorts
    unsigned short* Webf = Qbf + 5570560;                          // 1,048,576 shorts
    unsigned short* Xbf  = Webf + 1048576;                         // 5,570,560 shorts
    unsigned short* Wvbf = Xbf + 5570560;                          // 65,536 shorts
    unsigned short* OWbf = Wvbf + 65536;                           // 65,536 shorts
    unsigned short* Rbf  = OWbf + 65536;                           // 65,536 shorts
    unsigned short* atnb = Xbf;   // alias: Xbf consumed by k_value_mfma before k_sample writes

    k_cvt2<<<dim3(5440, 2), 256, 0, stream>>>(query, Qbf, inflat, Xbf, MTOT * 256 / 4);
    k_cvt3<<<dim3(1024, 3), 256, 0, stream>>>(We, Webf, OEN * 256 / 4,
                                              VW, Wvbf, 256 * 256 / 4,
                                              OW, OWbf, 256 * 256 / 4);
    k_prep_r<<<dim3(256), 256, 0, stream>>>(SW, AWw, Rbf);

    k_value_mfma<<<dim3(2, MTOT / 128), 256, 0, stream>>>(Xbf, Wvbf, Vb, Vtb);

    k_oe_mfma<<<dim3(OEN / 128, MTOT / 128), 256, 0, stream>>>(
        Qbf, Webf, Rbf, SB, ABb, offs, awl);

    k_sample<<<dim3(MTOT / 4), 256, 0, stream>>>(Vtb, refp, offs, awl, atnb);

    k_out_mfma<<<dim3(2, MTOT / 128), 256, 0, stream>>>(atnb, OWbf, Ob, out);
}

// Round 6
// 251.593 us; speedup vs baseline: 3.5665x; 1.0360x over previous
//
#include <hip/hip_runtime.h>
#include <hip/hip_bf16.h>

// ---------------- problem constants (static pyramid) ----------------
#define NB 4
#define LQ 5440
#define DM 256
#define NH 8
#define NL 4
#define NP 4
#define OFFD 32
#define DH 32
#define MTOT (NB * LQ)             // 21760
#define OEN (NH * NL * NP * OFFD)  // 4096
#define NGRP (NH * NL * NP)        // 128

typedef __attribute__((ext_vector_type(8))) short bf16x8;
typedef __attribute__((ext_vector_type(4))) float f32x4;
typedef unsigned int u32;

#define GLOAD_LDS16(gp, lp) \
    __builtin_amdgcn_global_load_lds((const __attribute__((address_space(1))) u32*)(gp), \
                                     (__attribute__((address_space(3))) u32*)(lp), 16, 0, 0)

__device__ __forceinline__ float bf2f(unsigned short u) {
    union { unsigned int i; float f; } v; v.i = ((unsigned int)u) << 16; return v.f;
}
// cheap RNE f32->bf16 (no NaN path; all values finite here)
__device__ __forceinline__ unsigned short f2bf(float x) {
    u32 u = __float_as_uint(x);
    u = u + 0x7fffu + ((u >> 16) & 1u);
    return (unsigned short)(u >> 16);
}
__device__ __forceinline__ u32 pk2(float a, float b) {
    u32 ua = __float_as_uint(a), ub = __float_as_uint(b);
    ua = ua + 0x7fffu + ((ua >> 16) & 1u);
    ub = ub + 0x7fffu + ((ub >> 16) & 1u);
    return (ua >> 16) | (ub & 0xffff0000u);
}
__device__ __forceinline__ float silu(float x) {
    float e = __expf(-x);
    return x * __builtin_amdgcn_rcpf(1.0f + e);   // v_rcp_f32, ~1 ulp
}

// ---------------- fp32 -> bf16 conversions ----------------
__global__ __launch_bounds__(256) void k_cvt2(
    const float* __restrict__ A, unsigned short* __restrict__ Ao,
    const float* __restrict__ B, unsigned short* __restrict__ Bo, int n4)
{
    int i = blockIdx.x * 256 + threadIdx.x;
    if (i >= n4) return;
    const float* src = blockIdx.y ? B : A;
    unsigned short* dst = blockIdx.y ? Bo : Ao;
    float4 v = *(const float4*)(src + (size_t)i * 4);
    ushort4 o;
    o.x = f2bf(v.x); o.y = f2bf(v.y); o.z = f2bf(v.z); o.w = f2bf(v.w);
    *(ushort4*)(dst + (size_t)i * 4) = o;
}
// weight tensors + Rb prepack (y==3)
__global__ __launch_bounds__(256) void k_cvt3(
    const float* __restrict__ A, unsigned short* __restrict__ Ao, int nA4,
    const float* __restrict__ B, unsigned short* __restrict__ Bo, int nB4,
    const float* __restrict__ C, unsigned short* __restrict__ Co, int nC4,
    const float* __restrict__ SW, const float* __restrict__ AW,
    unsigned short* __restrict__ Rb)
{
    int i = blockIdx.x * 256 + threadIdx.x;
    if (blockIdx.y == 3) {
        // Rb[gg][j16][d32]: j=0 SW.x, j=1 SW.y, j=2 AW, else 0   (65536 elems)
        if (i < 65536) {
            int gg = i >> 9, jo = (i >> 5) & 15, d = i & 31;
            float v = 0.f;
            if (jo == 0)      v = SW[(gg * 32 + d) * 2 + 0];
            else if (jo == 1) v = SW[(gg * 32 + d) * 2 + 1];
            else if (jo == 2) v = AW[gg * 32 + d];
            Rb[i] = f2bf(v);
        }
        return;
    }
    const float* src; unsigned short* dst; int n4;
    if (blockIdx.y == 0)      { src = A; dst = Ao; n4 = nA4; }
    else if (blockIdx.y == 1) { src = B; dst = Bo; n4 = nB4; }
    else                      { src = C; dst = Co; n4 = nC4; }
    if (i >= n4) return;
    float4 v = *(const float4*)(src + (size_t)i * 4);
    ushort4 o;
    o.x = f2bf(v.x); o.y = f2bf(v.y); o.z = f2bf(v.z); o.w = f2bf(v.w);
    *(ushort4*)(dst + (size_t)i * 4) = o;
}

// ============================================================================
// Stage B: MFMA bf16 GEMM (A=We, B=Q -> acc n-major) + silu + MFMA reduction.
// Staging XOR swizzle: chunk c (16B) at LDS slot (row=c>>3, q=c&7) holds
// GLOBAL chunk (row, q ^ (row&7)); reader of (row,kq) reads slot kq^(row&7).
// C/D layout (verified): col = lane&15, row = (lane>>4)*4 + reg.
// ============================================================================
__global__ __launch_bounds__(256) void k_oe_mfma(
    const unsigned short* __restrict__ Qb,   // (21760,256) bf16
    const unsigned short* __restrict__ Wb,   // (4096,256) bf16
    const unsigned short* __restrict__ Rb,   // (128,16,32) bf16 reduction frags
    const float* __restrict__ SB,    // (128,2)
    const float* __restrict__ AB,    // (128)
    float* __restrict__ offs_out,    // (M,128,2)
    float* __restrict__ aw_out)      // (M,128)
{
    __shared__ short sA[128 * 64];   // Q rows
    __shared__ short sB[128 * 64];   // We rows
    int tid = threadIdx.x;
    int n0 = blockIdx.x * 128;   // We/n fastest-varying -> blocks share Q via L2
    int m0 = blockIdx.y * 128;

    int lane = tid & 63;
    int w = tid >> 6;
    int wA = w >> 1;            // We half (mfma-m)
    int wB = w & 1;             // Q half (mfma-n)
    int lcol = lane & 15, quad = lane >> 4;

    int srow = tid >> 3;
    int sq = (tid & 7) ^ (srow & 7);
    const short* gA = (const short*)Qb + (size_t)(m0 + srow) * 256 + sq * 8;
    const short* gB = (const short*)Wb + (size_t)(n0 + srow) * 256 + sq * 8;
    short* lA = sA + w * 512;
    short* lB = sB + w * 512;

    f32x4 acc[4][4] = {};   // [We-tile i][Q-tile j]

    const short* pq = sA + (wB * 64 + lcol) * 64;   // Q fragments (B operand)
    const short* pw = sB + (wA * 64 + lcol) * 64;   // We fragments (A operand)
    int rx7 = lcol & 7;
    int qa0 = (quad ^ rx7) * 8;
    int qa1 = ((4 + quad) ^ rx7) * 8;

    for (int kc = 0; kc < 256; kc += 64) {
#pragma unroll
        for (int j = 0; j < 4; j++) {
            GLOAD_LDS16(gA + kc + j * 32 * 256, lA + j * 2048);
            GLOAD_LDS16(gB + kc + j * 32 * 256, lB + j * 2048);
        }
        __syncthreads();
        bf16x8 a[4][2], b[4][2];
#pragma unroll
        for (int i = 0; i < 4; i++) {
            a[i][0] = *(const bf16x8*)(pw + i * 16 * 64 + qa0);  // We
            a[i][1] = *(const bf16x8*)(pw + i * 16 * 64 + qa1);
            b[i][0] = *(const bf16x8*)(pq + i * 16 * 64 + qa0);  // Q
            b[i][1] = *(const bf16x8*)(pq + i * 16 * 64 + qa1);
        }
#pragma unroll
        for (int kh = 0; kh < 2; kh++)
#pragma unroll
            for (int i = 0; i < 4; i++)
#pragma unroll
                for (int j = 0; j < 4; j++)
                    acc[i][j] = __builtin_amdgcn_mfma_f32_16x16x32_bf16(
                        a[i][kh], b[j][kh], acc[i][j], 0, 0, 0);
        __syncthreads();
    }

    // ---- epilogue: silu -> bf16 pack (registers) -> MFMA reduction ----
    u32 ps[4][4][2];
#pragma unroll
    for (int i = 0; i < 4; i++)
#pragma unroll
        for (int j = 0; j < 4; j++) {
            ps[i][j][0] = pk2(silu(acc[i][j][0]), silu(acc[i][j][1]));
            ps[i][j][1] = pk2(silu(acc[i][j][2]), silu(acc[i][j][3]));
        }

    int srcbase = (quad & 1) * 32 + lcol;
    bool hi = quad >= 2;
    f32x4 zero = {};
#pragma unroll
    for (int g = 0; g < 2; g++) {
        int gg = (n0 + wA * 64 + g * 32) >> 5;
        bf16x8 afrag = *(const bf16x8*)(Rb + ((size_t)(gg * 16 + lcol) * 32 + quad * 8));
        float sb0 = SB[gg * 2 + 0], sb1 = SB[gg * 2 + 1], ab = AB[gg];
#pragma unroll
        for (int j = 0; j < 4; j++) {
            union { u32 u[4]; bf16x8 v; } bf;
#pragma unroll
            for (int b = 0; b < 2; b++) {
                int s = srcbase + b * 16;
#pragma unroll
                for (int c = 0; c < 2; c++) {
                    u32 x0 = (u32)__shfl((int)ps[2 * g + 0][j][c], s);
                    u32 x1 = (u32)__shfl((int)ps[2 * g + 1][j][c], s);
                    bf.u[b * 2 + c] = hi ? x1 : x0;
                }
            }
            f32x4 d2 = __builtin_amdgcn_mfma_f32_16x16x32_bf16(afrag, bf.v, zero, 0, 0, 0);
            if (quad == 0) {
                int m = m0 + wB * 64 + j * 16 + lcol;
                size_t oi = ((size_t)m * NGRP + gg) * 2;
                offs_out[oi + 0] = d2[0] + sb0;
                offs_out[oi + 1] = d2[1] + sb1;
                aw_out[(size_t)m * NGRP + gg] = d2[2] + ab;
            }
        }
    }
}

// ---------------- stage A: value projection (bf16 MFMA, swapped operands) ----
// A = Wv rows -> acc n-major: per tile the 4 regs are 4 CONSECUTIVE d of one
// head -> pack uint2, 16 x 8B stores per thread (was 64 scalar ushort).
__global__ __launch_bounds__(256) void k_value_mfma(
    const unsigned short* __restrict__ Xb,   // (21760,256) bf16
    const unsigned short* __restrict__ Wvb,  // (256,256) bf16 (n,k)
    const float* __restrict__ bias,          // (256)
    unsigned short* __restrict__ Vtb)        // (4,8,5440,32) bf16
{
    __shared__ short sA[128 * 64];   // X rows
    __shared__ short sB[128 * 64];   // Wv rows
    int tid = threadIdx.x;
    int n0 = blockIdx.x * 128;
    int m0 = blockIdx.y * 128;
    int lane = tid & 63;
    int w = tid >> 6;
    int wA = w >> 1;            // Wv half (mfma-m)
    int wB = w & 1;             // X half (mfma-n)
    int lcol = lane & 15, quad = lane >> 4;

    int srow = tid >> 3;
    int sq = (tid & 7) ^ (srow & 7);
    const short* gA = (const short*)Xb + (size_t)(m0 + srow) * 256 + sq * 8;
    const short* gB = (const short*)Wvb + (size_t)(n0 + srow) * 256 + sq * 8;
    short* lA = sA + w * 512;
    short* lB = sB + w * 512;

    f32x4 acc[4][4] = {};   // [Wv-tile i][X-tile j]
    const short* px = sA + (wB * 64 + lcol) * 64;
    const short* pw = sB + (wA * 64 + lcol) * 64;
    int rx7 = lcol & 7;
    int qa0 = (quad ^ rx7) * 8;
    int qa1 = ((4 + quad) ^ rx7) * 8;

    for (int kc = 0; kc < 256; kc += 64) {
#pragma unroll
        for (int j = 0; j < 4; j++) {
            GLOAD_LDS16(gA + kc + j * 32 * 256, lA + j * 2048);
            GLOAD_LDS16(gB + kc + j * 32 * 256, lB + j * 2048);
        }
        __syncthreads();
        bf16x8 a[4][2], b[4][2];
#pragma unroll
        for (int i = 0; i < 4; i++) {
            a[i][0] = *(const bf16x8*)(pw + i * 16 * 64 + qa0);  // Wv
            a[i][1] = *(const bf16x8*)(pw + i * 16 * 64 + qa1);
            b[i][0] = *(const bf16x8*)(px + i * 16 * 64 + qa0);  // X
            b[i][1] = *(const bf16x8*)(px + i * 16 * 64 + qa1);
        }
#pragma unroll
        for (int kh = 0; kh < 2; kh++)
#pragma unroll
            for (int i = 0; i < 4; i++)
#pragma unroll
                for (int j = 0; j < 4; j++)
                    acc[i][j] = __builtin_amdgcn_mfma_f32_16x16x32_bf16(
                        a[i][kh], b[j][kh], acc[i][j], 0, 0, 0);
        __syncthreads();
    }

#pragma unroll
    for (int i = 0; i < 4; i++) {
        int nb = n0 + wA * 64 + i * 16 + quad * 4;   // 4 consecutive n
        int h = nb >> 5, db = nb & 31;
        float4 b4 = *(const float4*)&bias[nb];
#pragma unroll
        for (int j = 0; j < 4; j++) {
            int m = m0 + wB * 64 + j * 16 + lcol;
            int b = m / LQ, q = m - b * LQ;
            u32 lo = pk2(acc[i][j][0] + b4.x, acc[i][j][1] + b4.y);
            u32 hi2 = pk2(acc[i][j][2] + b4.z, acc[i][j][3] + b4.w);
            char* dst = (char*)Vtb + ((((size_t)b * NH + h) * LQ + q) * DH + db) * 2;
            *(uint2*)dst = make_uint2(lo, hi2);
        }
    }
}

// ---------------- stage D: output projection (bf16 MFMA) ----------------
__global__ __launch_bounds__(256) void k_out_mfma(
    const unsigned short* __restrict__ Xb,   // (21760,256) bf16 attn
    const unsigned short* __restrict__ Wob,  // (256,256) bf16 (n,k)
    const float* __restrict__ bias,          // (256)
    float* __restrict__ Out)                 // (21760,256) fp32
{
    __shared__ short sA[128 * 64];
    __shared__ short sB[128 * 64];
    int tid = threadIdx.x;
    int n0 = blockIdx.x * 128;
    int m0 = blockIdx.y * 128;
    int lane = tid & 63;
    int w = tid >> 6;
    int wm = w >> 1, wn = w & 1;
    int lcol = lane & 15, lrow = lane >> 4;

    int srow = tid >> 3;
    int sq = (tid & 7) ^ (srow & 7);
    const short* gA = (const short*)Xb + (size_t)(m0 + srow) * 256 + sq * 8;
    const short* gB = (const short*)Wob + (size_t)(n0 + srow) * 256 + sq * 8;
    short* lA = sA + w * 512;
    short* lB = sB + w * 512;

    f32x4 acc[4][4] = {};
    const short* pa = sA + (wm * 64 + lcol) * 64;
    const short* pb = sB + (wn * 64 + lcol) * 64;
    int rx7 = lcol & 7;
    int qa0 = (lrow ^ rx7) * 8;
    int qa1 = ((4 + lrow) ^ rx7) * 8;

    for (int kc = 0; kc < 256; kc += 64) {
#pragma unroll
        for (int j = 0; j < 4; j++) {
            GLOAD_LDS16(gA + kc + j * 32 * 256, lA + j * 2048);
            GLOAD_LDS16(gB + kc + j * 32 * 256, lB + j * 2048);
        }
        __syncthreads();
        bf16x8 a[4][2], b[4][2];
#pragma unroll
        for (int i = 0; i < 4; i++) {
            a[i][0] = *(const bf16x8*)(pa + i * 16 * 64 + qa0);
            a[i][1] = *(const bf16x8*)(pa + i * 16 * 64 + qa1);
            b[i][0] = *(const bf16x8*)(pb + i * 16 * 64 + qa0);
            b[i][1] = *(const bf16x8*)(pb + i * 16 * 64 + qa1);
        }
#pragma unroll
        for (int kh = 0; kh < 2; kh++)
#pragma unroll
            for (int mi = 0; mi < 4; mi++)
#pragma unroll
                for (int ni = 0; ni < 4; ni++)
                    acc[mi][ni] = __builtin_amdgcn_mfma_f32_16x16x32_bf16(
                        a[mi][kh], b[ni][kh], acc[mi][ni], 0, 0, 0);
        __syncthreads();
    }

#pragma unroll
    for (int mi = 0; mi < 4; mi++) {
#pragma unroll
        for (int ni = 0; ni < 4; ni++) {
            int n = n0 + wn * 64 + ni * 16 + lcol;
            float bn = bias[n];
#pragma unroll
            for (int r = 0; r < 4; r++) {
                int m = m0 + wm * 64 + mi * 16 + lrow * 4 + r;
                Out[(size_t)m * 256 + n] = acc[mi][ni][r] + bn;
            }
        }
    }
}

// ---------------- stage C: softmax + bilinear sampling ----------------
// Block = 4 waves = 4 queries. Gather: lane = (p8=lane>>3, seg=lane&7);
// dwordx2 per lane -> one instr covers 8 point-rows x 64 B (one corner).
// Corners accumulated in-register (no shuffles); point-reduce = 3 xor rounds.
__global__ __launch_bounds__(256) void k_sample(
    const unsigned short* __restrict__ Vtb,  // (4,8,5440,32) bf16
    const float* __restrict__ refp,          // (4,5440,4,2)
    const float* __restrict__ offs,          // (M,128,2)
    const float* __restrict__ awl,           // (M,128)
    unsigned short* __restrict__ atnb)       // (M,256) bf16
{
    int tid = threadIdx.x;
    int m_base = blockIdx.x * 4;
    __shared__ int2 s_iw[4][128][4];   // {byte row offset, weight bits}

    // ---- prep: 512 (mloc,point) pairs on 256 threads, 2 reps ----
#pragma unroll
    for (int rep = 0; rep < 2; rep++) {
        int p = tid & 127;
        int mloc = (tid >> 7) + rep * 2;
        int m = m_base + mloc;
        int l = (p >> 2) & 3;
        float logit = awl[(size_t)m * 128 + p];
        float mx = logit;
#pragma unroll
        for (int off = 1; off < 16; off <<= 1) mx = fmaxf(mx, __shfl_xor(mx, off));
        float e = __expf(logit - mx);
        float s = e;
#pragma unroll
        for (int off = 1; off < 16; off <<= 1) s += __shfl_xor(s, off);
        float prob = e * __builtin_amdgcn_rcpf(s);

        float ox = offs[((size_t)m * 128 + p) * 2 + 0];
        float oy = offs[((size_t)m * 128 + p) * 2 + 1];
        float rx = refp[(size_t)m * 8 + l * 2 + 0];
        float ry = refp[(size_t)m * 8 + l * 2 + 1];
        int Wl = 64 >> l;
        int base = (l == 0) ? 0 : (l == 1) ? 4096 : (l == 2) ? 5120 : 5376;
        float fW = (float)Wl;
        float x = rx * fW + ox - 0.5f;
        float y = ry * fW + oy - 0.5f;
        float x0f = floorf(x), y0f = floorf(y);
        float wx = x - x0f, wy = y - y0f;
        int x0 = (int)x0f, y0 = (int)y0f;
        int xc0 = min(max(x0, 0), Wl - 1), xc1 = min(max(x0 + 1, 0), Wl - 1);
        int yc0 = min(max(y0, 0), Wl - 1), yc1 = min(max(y0 + 1, 0), Wl - 1);
        float vx0 = (x0 >= 0 && x0 < Wl) ? 1.f : 0.f;
        float vx1 = (x0 + 1 < Wl) ? 1.f : 0.f;
        float vy0 = (y0 >= 0 && y0 < Wl) ? 1.f : 0.f;
        float vy1 = (y0 + 1 < Wl) ? 1.f : 0.f;
        if (x0 + 1 < 0) vx1 = 0.f;
        if (y0 + 1 < 0) vy1 = 0.f;
        s_iw[mloc][p][0] = make_int2((base + yc0 * Wl + xc0) * 64,
                                     __float_as_int(prob * (1.f - wx) * (1.f - wy) * vx0 * vy0));
        s_iw[mloc][p][1] = make_int2((base + yc0 * Wl + xc1) * 64,
                                     __float_as_int(prob * wx * (1.f - wy) * vx1 * vy0));
        s_iw[mloc][p][2] = make_int2((base + yc1 * Wl + xc0) * 64,
                                     __float_as_int(prob * (1.f - wx) * wy * vx0 * vy1));
        s_iw[mloc][p][3] = make_int2((base + yc1 * Wl + xc1) * 64,
                                     __float_as_int(prob * wx * wy * vx1 * vy1));
    }
    __syncthreads();

    // ---- gather ----
    int wv = tid >> 6, lane = tid & 63;
    int p8 = lane >> 3, seg = lane & 7;   // seg: 8B = 4 channels
    int m = m_base + wv;
    int b = m / LQ;
    const char* vB = (const char*)(Vtb + (size_t)b * NH * LQ * DH) + seg * 8;
#pragma unroll
    for (int h = 0; h < 8; h++) {
        const char* ph = vB + (size_t)h * (LQ * DH * 2);
        float a0 = 0.f, a1 = 0.f, a2 = 0.f, a3 = 0.f;
#pragma unroll
        for (int pg = 0; pg < 2; pg++) {
            int p = h * 16 + pg * 8 + p8;
#pragma unroll
            for (int c = 0; c < 4; c++) {
                int2 iw = s_iw[wv][p][c];
                uint2 v = *(const uint2*)(ph + iw.x);
                float wgt = __int_as_float(iw.y);
                a0 += wgt * __uint_as_float(v.x << 16);
                a1 += wgt * __uint_as_float(v.x & 0xffff0000u);
                a2 += wgt * __uint_as_float(v.y << 16);
                a3 += wgt * __uint_as_float(v.y & 0xffff0000u);
            }
        }
        // reduce over the 8 point-rows (lane bits 3,4,5)
#pragma unroll
        for (int off = 8; off <= 32; off <<= 1) {
            a0 += __shfl_xor(a0, off);
            a1 += __shfl_xor(a1, off);
            a2 += __shfl_xor(a2, off);
            a3 += __shfl_xor(a3, off);
        }
        if (p8 == 0) {
            ((uint2*)atnb)[(size_t)m * 64 + h * 8 + seg] =
                make_uint2(pk2(a0, a1), pk2(a2, a3));
        }
    }
}

// ---------------- launch ----------------
extern "C" void kernel_launch(void* const* d_in, const int* in_sizes, int n_in,
                              void* d_out, int out_size, void* d_ws, size_t ws_size,
                              hipStream_t stream) {
    const float* query  = (const float*)d_in[0];
    const float* refp   = (const float*)d_in[1];
    const float* inflat = (const float*)d_in[2];
    // d_in[3] = input_spatial_shapes (static, unused)
    const float* We  = (const float*)d_in[4];
    const float* SW  = (const float*)d_in[5];
    const float* SB  = (const float*)d_in[6];
    const float* AWw = (const float*)d_in[7];
    const float* ABb = (const float*)d_in[8];
    const float* VW  = (const float*)d_in[9];
    const float* Vb  = (const float*)d_in[10];
    const float* OW  = (const float*)d_in[11];
    const float* Ob  = (const float*)d_in[12];
    float* out = (float*)d_out;

    float* ws = (float*)d_ws;
    unsigned short* Vtb  = (unsigned short*)ws;                    // 5,570,560 shorts
    float* offs          = ws + 2785280;                           // 5,570,560 f
    float* awl           = offs + 5570560;                         // 2,785,280 f
    unsigned short* Qbf  = (unsigned short*)(awl + 2785280);       // 5,570,560 shorts
    unsigned short* Webf = Qbf + 5570560;                          // 1,048,576 shorts
    unsigned short* Xbf  = Webf + 1048576;                         // 5,570,560 shorts
    unsigned short* Wvbf = Xbf + 5570560;                          // 65,536 shorts
    unsigned short* OWbf = Wvbf + 65536;                           // 65,536 shorts
    unsigned short* Rbf  = OWbf + 65536;                           // 65,536 shorts
    unsigned short* atnb = Xbf;   // alias: Xbf consumed by k_value_mfma before k_sample writes

    k_cvt2<<<dim3(5440, 2), 256, 0, stream>>>(query, Qbf, inflat, Xbf, MTOT * 256 / 4);
    k_cvt3<<<dim3(1024, 4), 256, 0, stream>>>(We, Webf, OEN * 256 / 4,
                                              VW, Wvbf, 256 * 256 / 4,
                                              OW, OWbf, 256 * 256 / 4,
                                              SW, AWw, Rbf);

    k_value_mfma<<<dim3(2, MTOT / 128), 256, 0, stream>>>(Xbf, Wvbf, Vb, Vtb);

    k_oe_mfma<<<dim3(OEN / 128, MTOT / 128), 256, 0, stream>>>(
        Qbf, Webf, Rbf, SB, ABb, offs, awl);

    k_sample<<<dim3(MTOT / 4), 256, 0, stream>>>(Vtb, refp, offs, awl, atnb);

    k_out_mfma<<<dim3(2, MTOT / 128), 256, 0, stream>>>(atnb, OWbf, Ob, out);
}